// Round 5
// baseline (1661.237 us; speedup 1.0000x reference)
//
#include <hip/hip_runtime.h>
#include <math.h>

#define NN  50000
#define NE  400000
#define NTE 50000
#define FIN 64
#define EDIM 32
#define HD  128
#define NL  2
#define SCAN_B ((NN + 255) / 256)

typedef __attribute__((ext_vector_type(8))) short bf16x8;
typedef __attribute__((ext_vector_type(4))) float f32x4;

static __device__ __forceinline__ unsigned short f2bf(float f) {
    unsigned u = __float_as_uint(f);
    unsigned r = (u + 0x7fffu + ((u >> 16) & 1u)) >> 16;
    return (unsigned short)r;
}
static __device__ __forceinline__ float bfhi2f(unsigned u) { return __uint_as_float(u & 0xffff0000u); }
static __device__ __forceinline__ float bflo2f(unsigned u) { return __uint_as_float(u << 16); }

static __device__ __forceinline__ bf16x8 load_a8(const float* p, bool ok) {
    bf16x8 a = {};
    if (ok) {
        const float4 v0 = *(const float4*)(p);
        const float4 v1 = *(const float4*)(p + 4);
        a[0] = (short)f2bf(v0.x); a[1] = (short)f2bf(v0.y);
        a[2] = (short)f2bf(v0.z); a[3] = (short)f2bf(v0.w);
        a[4] = (short)f2bf(v1.x); a[5] = (short)f2bf(v1.y);
        a[6] = (short)f2bf(v1.z); a[7] = (short)f2bf(v1.w);
    }
    return a;
}
static __device__ __forceinline__ bf16x8 pack8(float4 a, float4 b) {
    bf16x8 v;
    v[0]=(short)f2bf(a.x); v[1]=(short)f2bf(a.y); v[2]=(short)f2bf(a.z); v[3]=(short)f2bf(a.w);
    v[4]=(short)f2bf(b.x); v[5]=(short)f2bf(b.y); v[6]=(short)f2bf(b.z); v[7]=(short)f2bf(b.w);
    return v;
}

// ---- pack fp32 W[K][128] into bf16 MFMA B-frag order: [(kb*8+nt)*64+lane][8] k-contig ----
__global__ void __launch_bounds__(256) k_packW(const float* __restrict__ W,
        unsigned short* __restrict__ out, int K)
{
    const int tid = blockIdx.x * 256 + threadIdx.x;
    const int total = (K / 32) * 512;
    if (tid >= total) return;
    const int lane = tid & 63, nt = (tid >> 6) & 7, kb = tid >> 9;
    const int k0 = kb * 32 + (lane >> 4) * 8;
    const int col = nt * 16 + (lane & 15);
    bf16x8 v;
    #pragma unroll
    for (int j = 0; j < 8; ++j)
        v[j] = (short)f2bf(W[(size_t)(k0 + j) * HD + col]);
    *(bf16x8*)(out + (size_t)tid * 8) = v;
}

// ---- MFMA GEMM (single output, guarded): C = A@W (+bias) ----
template<int KB>
__global__ void __launch_bounds__(256) k_gemm_mfma(const float* A,
        const unsigned short* __restrict__ Wpk, const float* __restrict__ bias,
        float* C, int M)
{
    const int t = threadIdx.x, w = t >> 6, l = t & 63;
    const int row0 = blockIdx.x * 64 + w * 16;
    const int ar = row0 + (l & 15);
    const bool aok = ar < M;
    const int kq = (l >> 4) * 8;
    const int K = KB * 32;
    f32x4 acc[8] = {};
    #pragma unroll
    for (int kb = 0; kb < KB; ++kb) {
        const bf16x8 a = load_a8(A + (size_t)ar * K + kb * 32 + kq, aok);
        #pragma unroll
        for (int nt = 0; nt < 8; ++nt) {
            const bf16x8 b = *(const bf16x8*)(Wpk + (((size_t)(kb * 8 + nt) * 64 + l) << 3));
            acc[nt] = __builtin_amdgcn_mfma_f32_16x16x32_bf16(a, b, acc[nt], 0, 0, 0);
        }
    }
    #pragma unroll
    for (int nt = 0; nt < 8; ++nt) {
        const int col = nt * 16 + (l & 15);
        const float bv = bias ? bias[col] : 0.f;
        #pragma unroll
        for (int r = 0; r < 4; ++r) {
            const int orow = row0 + (l >> 4) * 4 + r;
            if (orow < M) C[(size_t)orow * HD + col] = acc[nt][r] + bv;
        }
    }
}

// ---- MFMA GEMM dual output: C0 = A@W0 + b0, C1 = A@W1 ----
template<int KB>
__global__ void __launch_bounds__(256) k_gemm2_mfma(const float* A,
        const unsigned short* __restrict__ W0, const unsigned short* __restrict__ W1,
        const float* __restrict__ b0, float* C0, float* C1, int M)
{
    const int t = threadIdx.x, w = t >> 6, l = t & 63;
    const int row0 = blockIdx.x * 64 + w * 16;
    const int ar = row0 + (l & 15);
    const bool aok = ar < M;
    const int kq = (l >> 4) * 8;
    const int K = KB * 32;
    f32x4 a0[8] = {}, a1[8] = {};
    #pragma unroll
    for (int kb = 0; kb < KB; ++kb) {
        const bf16x8 a = load_a8(A + (size_t)ar * K + kb * 32 + kq, aok);
        #pragma unroll
        for (int nt = 0; nt < 8; ++nt) {
            const bf16x8 u = *(const bf16x8*)(W0 + (((size_t)(kb * 8 + nt) * 64 + l) << 3));
            const bf16x8 v = *(const bf16x8*)(W1 + (((size_t)(kb * 8 + nt) * 64 + l) << 3));
            a0[nt] = __builtin_amdgcn_mfma_f32_16x16x32_bf16(a, u, a0[nt], 0, 0, 0);
            a1[nt] = __builtin_amdgcn_mfma_f32_16x16x32_bf16(a, v, a1[nt], 0, 0, 0);
        }
    }
    #pragma unroll
    for (int nt = 0; nt < 8; ++nt) {
        const int col = nt * 16 + (l & 15);
        const float bv = b0 ? b0[col] : 0.f;
        #pragma unroll
        for (int r = 0; r < 4; ++r) {
            const int orow = row0 + (l >> 4) * 4 + r;
            if (orow < M) {
                C0[(size_t)orow * HD + col] = a0[nt][r] + bv;
                C1[(size_t)orow * HD + col] = a1[nt][r];
            }
        }
    }
}

// ---- degree count ----
__global__ void __launch_bounds__(256) k_count(const int* __restrict__ d, int* __restrict__ cnt, int E)
{
    const int e = blockIdx.x * 256 + threadIdx.x;
    if (e < E) atomicAdd(&cnt[d[e]], 1);
}

// ---- mean(log(cnt+1)) numerator ----
__global__ void __launch_bounds__(256) k_avglog(const int* __restrict__ cnt, float* __restrict__ stats)
{
    float s = 0.f;
    for (int n = blockIdx.x * 256 + threadIdx.x; n < NN; n += gridDim.x * 256)
        s += logf((float)cnt[n] + 1.f);
    #pragma unroll
    for (int off = 32; off > 0; off >>= 1) s += __shfl_down(s, off);
    __shared__ float ls[4];
    if ((threadIdx.x & 63) == 0) ls[threadIdx.x >> 6] = s;
    __syncthreads();
    if (threadIdx.x == 0) unsafeAtomicAdd(stats, ls[0] + ls[1] + ls[2] + ls[3]);
}

// ---- CSR build ----
__global__ void __launch_bounds__(256) k_scan_block(const int* __restrict__ cnt,
        int* __restrict__ incl, int* __restrict__ part)
{
    __shared__ int s[256];
    const int t = threadIdx.x;
    const int i = blockIdx.x * 256 + t;
    const int v = (i < NN) ? cnt[i] : 0;
    s[t] = v;
    __syncthreads();
    #pragma unroll
    for (int off = 1; off < 256; off <<= 1) {
        const int x = (t >= off) ? s[t - off] : 0;
        __syncthreads();
        s[t] += x;
        __syncthreads();
    }
    if (i < NN) incl[i] = s[t];
    if (t == 255) part[blockIdx.x] = s[255];
}

__global__ void __launch_bounds__(256) k_scan_part(const int* __restrict__ part,
        int* __restrict__ poff, int np)
{
    __shared__ int s[256];
    const int t = threadIdx.x;
    const int v = (t < np) ? part[t] : 0;
    s[t] = v;
    __syncthreads();
    #pragma unroll
    for (int off = 1; off < 256; off <<= 1) {
        const int x = (t >= off) ? s[t - off] : 0;
        __syncthreads();
        s[t] += x;
        __syncthreads();
    }
    poff[t] = s[t] - v;
}

__global__ void __launch_bounds__(256) k_scan_add(const int* __restrict__ incl,
        const int* __restrict__ cnt, const int* __restrict__ poff,
        int* __restrict__ row_start, int* __restrict__ cursor)
{
    const int i = blockIdx.x * 256 + threadIdx.x;
    if (i < NN) {
        const int excl = incl[i] - cnt[i] + poff[blockIdx.x];
        row_start[i] = excl;
        cursor[i] = excl;
    }
    if (i == 0) row_start[NN] = NE;
}

__global__ void __launch_bounds__(256) k_scatter(const int* __restrict__ dstp,
        int* cursor, int* __restrict__ sppos)
{
    const int e = blockIdx.x * 256 + threadIdx.x;
    if (e < NE) sppos[e] = atomicAdd(&cursor[dstp[e]], 1);
}

// ---- msg: m' = ea@We + xs[src] (xd[dst] applied later in k_agg — shift-equivariant agg) ----
// writes bf16 rows at CSR position. NE % 64 == 0 -> no guards.
__global__ void __launch_bounds__(256) k_msg_mfma(const float* __restrict__ ea,
        const unsigned short* __restrict__ Wepk, const float* __restrict__ xs,
        const int* __restrict__ srcp, const int* __restrict__ sppos,
        unsigned short* __restrict__ mbuf)
{
    __shared__ float s_acc[64][132];
    __shared__ int s_src[64], s_sp[64];
    const int t = threadIdx.x, w = t >> 6, l = t & 63;
    const int row0b = blockIdx.x * 64;
    if (t < 64) {
        s_src[t] = srcp[row0b + t];
        s_sp[t]  = sppos[row0b + t];
    }
    const int ar = row0b + w * 16 + (l & 15);
    const int kq = (l >> 4) * 8;
    const int colb = l & 15;
    f32x4 acc[8] = {};
    #pragma unroll
    for (int kb = 0; kb < 4; ++kb) {
        const bf16x8 a = load_a8(ea + (size_t)ar * HD + kb * 32 + kq, true);
        #pragma unroll
        for (int nt = 0; nt < 8; ++nt) {
            const bf16x8 b = *(const bf16x8*)(Wepk + (((size_t)(kb * 8 + nt) * 64 + l) << 3));
            acc[nt] = __builtin_amdgcn_mfma_f32_16x16x32_bf16(a, b, acc[nt], 0, 0, 0);
        }
    }
    #pragma unroll
    for (int nt = 0; nt < 8; ++nt)
        #pragma unroll
        for (int r = 0; r < 4; ++r)
            s_acc[w * 16 + (l >> 4) * 4 + r][nt * 16 + colb] = acc[nt][r];
    __syncthreads();
    const int rr = t >> 2, cg = (t & 3) * 32;
    const int sn = s_src[rr], sp = s_sp[rr];
    const float* ps = xs + (size_t)sn * HD + cg;
    unsigned short* pm = mbuf + (size_t)sp * HD + cg;
    #pragma unroll
    for (int i = 0; i < 4; ++i) {
        float4 a0 = *(const float4*)&s_acc[rr][cg + i * 8];
        float4 a1 = *(const float4*)&s_acc[rr][cg + i * 8 + 4];
        const float4 s0 = *(const float4*)(ps + i * 8);
        const float4 s1 = *(const float4*)(ps + i * 8 + 4);
        a0.x += s0.x; a0.y += s0.y; a0.z += s0.z; a0.w += s0.w;
        a1.x += s1.x; a1.y += s1.y; a1.z += s1.z; a1.w += s1.w;
        *(bf16x8*)(pm + i * 8) = pack8(a0, a1);
    }
}

// ---- CSR aggregation from bf16 m'; shift by xd[n]; bf16 agg out [NN][512] ----
__global__ void __launch_bounds__(256) k_agg(const unsigned short* __restrict__ mbuf,
        const int* __restrict__ rs, const float* __restrict__ xd,
        unsigned short* __restrict__ aggb)
{
    const int n = blockIdx.x * 4 + (threadIdx.x >> 6);
    if (n >= NN) return;
    const int lane = threadIdx.x & 63;
    const int c = lane * 2;
    const int s = rs[n], e = rs[n + 1];
    const float2 xv = *(const float2*)(xd + (size_t)n * HD + c);
    float s0=0.f, s1=0.f, q0=0.f, q1=0.f;
    float mn0=INFINITY, mn1=INFINITY, mx0=-INFINITY, mx1=-INFINITY;
    for (int i = s; i < e; ++i) {
        const unsigned u = *(const unsigned*)(mbuf + (size_t)i * HD + c);
        const float v0 = bflo2f(u), v1 = bfhi2f(u);
        s0 += v0; s1 += v1;
        q0 += v0 * v0; q1 += v1 * v1;
        mn0 = fminf(mn0, v0); mn1 = fminf(mn1, v1);
        mx0 = fmaxf(mx0, v0); mx1 = fmaxf(mx1, v1);
    }
    const int deg = e - s;
    const float inv = 1.f / (float)(deg > 1 ? deg : 1);
    const float fd = (float)deg * inv;          // 0 if deg==0 else 1
    const float m0p = s0 * inv, m1p = s1 * inv;
    const float sd0 = sqrtf(fmaxf(q0 * inv - m0p * m0p, 0.f) + 1e-5f);
    const float sd1 = sqrtf(fmaxf(q1 * inv - m1p * m1p, 0.f) + 1e-5f);
    const bool has = deg > 0;
    const float mean0 = m0p + fd * xv.x, mean1 = m1p + fd * xv.y;
    const float omn0 = has ? mn0 + xv.x : 0.f, omn1 = has ? mn1 + xv.y : 0.f;
    const float omx0 = has ? mx0 + xv.x : 0.f, omx1 = has ? mx1 + xv.y : 0.f;
    unsigned* a = (unsigned*)(aggb + (size_t)n * 512 + c);
    a[0]         = (unsigned)f2bf(mean0) | ((unsigned)f2bf(mean1) << 16);
    *(a + 64)    = (unsigned)f2bf(omn0)  | ((unsigned)f2bf(omn1)  << 16);
    *(a + 128)   = (unsigned)f2bf(omx0)  | ((unsigned)f2bf(omx1)  << 16);
    *(a + 192)   = (unsigned)f2bf(sd0)   | ((unsigned)f2bf(sd1)   << 16);
}

// ---- post fused with lin: out = [x|agg]@PW (amp/att scaled) + pb; outb = out@linW + lb ----
__global__ void __launch_bounds__(256) k_post_lin(const float* __restrict__ x,
        const unsigned short* __restrict__ aggb, const int* __restrict__ cnt,
        const float* __restrict__ stats, const unsigned short* __restrict__ PWpk,
        const float* __restrict__ pb, const unsigned short* __restrict__ LNpk,
        const float* __restrict__ lb, float* __restrict__ outb, int M)
{
    __shared__ float s_amp[64], s_att[64];
    __shared__ unsigned short s_o16[64 * 128];   // swizzled bf16 out tile
    const int t = threadIdx.x;
    const int row0b = blockIdx.x * 64;
    if (t < 64) {
        const int n = row0b + t;
        const float cf = (n < M) ? (float)cnt[n] : 1.f;
        const float avg = stats[0] * (1.f / (float)NN);
        const float lg = logf(fmaxf(cf, 1.f) + 1.f);
        s_amp[t] = lg / avg;
        s_att[t] = avg / lg;
    }
    __syncthreads();
    const int w = t >> 6, l = t & 63;
    const int row0 = row0b + w * 16;
    const int ar = row0 + (l & 15);
    const bool aok = ar < M;
    const int kq = (l >> 4) * 8;
    const int colb = l & 15;
    f32x4 aA[8] = {}, aB[8] = {}, aC[8] = {};

    #pragma unroll
    for (int kb = 0; kb < 4; ++kb) {
        const bf16x8 a = load_a8(x + (size_t)ar * HD + kb * 32 + kq, aok);
        #pragma unroll
        for (int nt = 0; nt < 8; ++nt) {
            const bf16x8 b = *(const bf16x8*)(PWpk + (((size_t)(kb * 8 + nt) * 64 + l) << 3));
            aA[nt] = __builtin_amdgcn_mfma_f32_16x16x32_bf16(a, b, aA[nt], 0, 0, 0);
        }
    }
    for (int jb = 0; jb < 4; ++jb) {
        #pragma unroll
        for (int k2 = 0; k2 < 4; ++k2) {
            bf16x8 a = {};
            if (aok) a = *(const bf16x8*)(aggb + (size_t)ar * 512 + jb * 128 + k2 * 32 + kq);
            const int kb1 = 4  + jb * 4 + k2;
            const int kb2 = 20 + jb * 4 + k2;
            const int kb3 = 36 + jb * 4 + k2;
            #pragma unroll
            for (int nt = 0; nt < 8; ++nt) {
                const bf16x8 b1 = *(const bf16x8*)(PWpk + (((size_t)(kb1 * 8 + nt) * 64 + l) << 3));
                const bf16x8 b2 = *(const bf16x8*)(PWpk + (((size_t)(kb2 * 8 + nt) * 64 + l) << 3));
                const bf16x8 b3 = *(const bf16x8*)(PWpk + (((size_t)(kb3 * 8 + nt) * 64 + l) << 3));
                aA[nt] = __builtin_amdgcn_mfma_f32_16x16x32_bf16(a, b1, aA[nt], 0, 0, 0);
                aB[nt] = __builtin_amdgcn_mfma_f32_16x16x32_bf16(a, b2, aB[nt], 0, 0, 0);
                aC[nt] = __builtin_amdgcn_mfma_f32_16x16x32_bf16(a, b3, aC[nt], 0, 0, 0);
            }
        }
    }
    // out -> swizzled bf16 LDS
    #pragma unroll
    for (int nt = 0; nt < 8; ++nt) {
        const int col = nt * 16 + colb;
        const float bv = pb[col];
        #pragma unroll
        for (int r = 0; r < 4; ++r) {
            const int lr = w * 16 + (l >> 4) * 4 + r;
            const float o = aA[nt][r] + s_amp[lr] * aB[nt][r] + s_att[lr] * aC[nt][r] + bv;
            const int ba = lr * 256 + ((((col >> 3)) ^ (lr & 7)) << 4) + ((col & 7) << 1);
            *(unsigned short*)((char*)s_o16 + ba) = f2bf(o);
        }
    }
    __syncthreads();
    // lin GEMM from LDS
    f32x4 lacc[8] = {};
    const int lrow = w * 16 + (l & 15);
    #pragma unroll
    for (int kb = 0; kb < 4; ++kb) {
        const int slot = kb * 4 + (l >> 4);
        const int ba = lrow * 256 + ((slot ^ (lrow & 7)) << 4);
        const bf16x8 a = *(const bf16x8*)((const char*)s_o16 + ba);
        #pragma unroll
        for (int nt = 0; nt < 8; ++nt) {
            const bf16x8 b = *(const bf16x8*)(LNpk + (((size_t)(kb * 8 + nt) * 64 + l) << 3));
            lacc[nt] = __builtin_amdgcn_mfma_f32_16x16x32_bf16(a, b, lacc[nt], 0, 0, 0);
        }
    }
    #pragma unroll
    for (int nt = 0; nt < 8; ++nt) {
        const int col = nt * 16 + colb;
        const float bv = lb[col];
        #pragma unroll
        for (int r = 0; r < 4; ++r) {
            const int orow = row0b + w * 16 + (l >> 4) * 4 + r;
            if (orow < M) outb[(size_t)orow * HD + col] = lacc[nt][r] + bv;
        }
    }
}

// ---- BN column sums ----
__global__ void __launch_bounds__(256) k_bnstats(const float* __restrict__ ob,
        float* __restrict__ bs, float* __restrict__ bq, int M)
{
    const int c = threadIdx.x & 127;
    const int gsub = threadIdx.x >> 7;
    float s = 0.f, qq = 0.f;
    for (int rr = blockIdx.x * 2 + gsub; rr < M; rr += gridDim.x * 2) {
        const float v = ob[(size_t)rr * HD + c];
        s += v; qq += v * v;
    }
    __shared__ float ls[2][HD], lq[2][HD];
    ls[gsub][c] = s; lq[gsub][c] = qq;
    __syncthreads();
    if (gsub == 0) {
        unsafeAtomicAdd(&bs[c], ls[0][c] + ls[1][c]);
        unsafeAtomicAdd(&bq[c], lq[0][c] + lq[1][c]);
    }
}

// ---- x = (x + relu(bn(out)))/2 ----
__global__ void __launch_bounds__(256) k_xupdate(float* x, const float* __restrict__ ob,
        const float* __restrict__ bs, const float* __restrict__ bq,
        const float* __restrict__ g, const float* __restrict__ bb)
{
    const int i = blockIdx.x * 256 + threadIdx.x;
    const int c0 = (i & 31) * 4;
    const float4 ov = ((const float4*)ob)[i];
    const float4 xv = ((const float4*)x)[i];
    const float o[4]  = {ov.x, ov.y, ov.z, ov.w};
    const float xo[4] = {xv.x, xv.y, xv.z, xv.w};
    float res[4];
    #pragma unroll
    for (int j = 0; j < 4; ++j) {
        const int c = c0 + j;
        const float mu  = bs[c] * (1.f / (float)NN);
        const float var = bq[c] * (1.f / (float)NN) - mu * mu;
        const float bn  = g[c] * (o[j] - mu) * rsqrtf(var + 1e-5f) + bb[c];
        res[j] = (xo[j] + fmaxf(bn, 0.f)) * 0.5f;
    }
    ((float4*)x)[i] = make_float4(res[0], res[1], res[2], res[3]);
}

// ---- edge update: single row-linear ea read; LDS-staged GEMMs; vectorized epilogues ----
__global__ void __launch_bounds__(256) k_edge_upd_mfma(float* ea,
        const unsigned short* __restrict__ W1epk, const unsigned short* __restrict__ e2pk,
        const float* __restrict__ e2b, const float* __restrict__ xs1,
        const float* __restrict__ xd1, const int* __restrict__ srcp,
        const int* __restrict__ dstp)
{
    __shared__ float s_acc[64][132];
    __shared__ unsigned short s_bf[64 * 128];   // swizzled bf16: ea tile, then hid tile
    __shared__ float s_b2[128];
    __shared__ int s_src[64], s_dst[64];
    const int t = threadIdx.x, w = t >> 6, l = t & 63;
    const int row0b = blockIdx.x * 64;
    if (t < 64) {
        s_src[t] = srcp[row0b + t];
        s_dst[t] = dstp[row0b + t];
    }
    if (t < 128) s_b2[t] = e2b[t];

    // phase 0: row-linear ea load -> regs (fp32) + swizzled bf16 LDS
    const int rr = t >> 2, cg = (t & 3) * 32;
    const int er = row0b + rr;
    float4 eo[8];
    {
        const float* pe = ea + (size_t)er * HD + cg;
        #pragma unroll
        for (int i = 0; i < 8; ++i) eo[i] = *(const float4*)(pe + i * 4);
        #pragma unroll
        for (int sdx = 0; sdx < 4; ++sdx) {
            const int slot = (cg >> 3) + sdx;
            const int ba = rr * 256 + ((slot ^ (rr & 7)) << 4);
            *(bf16x8*)((char*)s_bf + ba) = pack8(eo[sdx * 2], eo[sdx * 2 + 1]);
        }
    }
    __syncthreads();
    // GEMM1: hid_pre = ea @ W1e (A-frags from LDS)
    const int kq4 = l >> 4;
    const int lrow = w * 16 + (l & 15);
    const int colb = l & 15;
    f32x4 acc[8] = {};
    #pragma unroll
    for (int kb = 0; kb < 4; ++kb) {
        const int slot = kb * 4 + kq4;
        const int ba = lrow * 256 + ((slot ^ (lrow & 7)) << 4);
        const bf16x8 a = *(const bf16x8*)((const char*)s_bf + ba);
        #pragma unroll
        for (int nt = 0; nt < 8; ++nt) {
            const bf16x8 b = *(const bf16x8*)(W1epk + (((size_t)(kb * 8 + nt) * 64 + l) << 3));
            acc[nt] = __builtin_amdgcn_mfma_f32_16x16x32_bf16(a, b, acc[nt], 0, 0, 0);
        }
    }
    #pragma unroll
    for (int nt = 0; nt < 8; ++nt)
        #pragma unroll
        for (int r = 0; r < 4; ++r)
            s_acc[w * 16 + (l >> 4) * 4 + r][nt * 16 + colb] = acc[nt][r];
    __syncthreads();
    // epilogue1 (row-linear): hid = relu(acc + xs1[src] + xd1[dst]) -> swizzled bf16 LDS
    {
        const int sn = s_src[rr], dn = s_dst[rr];
        const float* ps = xs1 + (size_t)sn * HD + cg;
        const float* pd = xd1 + (size_t)dn * HD + cg;
        #pragma unroll
        for (int i = 0; i < 4; ++i) {
            float4 a0 = *(const float4*)&s_acc[rr][cg + i * 8];
            float4 a1 = *(const float4*)&s_acc[rr][cg + i * 8 + 4];
            const float4 s0 = *(const float4*)(ps + i * 8), s1 = *(const float4*)(ps + i * 8 + 4);
            const float4 d0 = *(const float4*)(pd + i * 8), d1 = *(const float4*)(pd + i * 8 + 4);
            a0.x = fmaxf(a0.x + s0.x + d0.x, 0.f); a0.y = fmaxf(a0.y + s0.y + d0.y, 0.f);
            a0.z = fmaxf(a0.z + s0.z + d0.z, 0.f); a0.w = fmaxf(a0.w + s0.w + d0.w, 0.f);
            a1.x = fmaxf(a1.x + s1.x + d1.x, 0.f); a1.y = fmaxf(a1.y + s1.y + d1.y, 0.f);
            a1.z = fmaxf(a1.z + s1.z + d1.z, 0.f); a1.w = fmaxf(a1.w + s1.w + d1.w, 0.f);
            const int slot = (cg >> 3) + i;
            const int ba = rr * 256 + ((slot ^ (rr & 7)) << 4);
            *(bf16x8*)((char*)s_bf + ba) = pack8(a0, a1);
        }
    }
    __syncthreads();
    // GEMM2: upd = hid @ em2
    f32x4 acc2[8] = {};
    #pragma unroll
    for (int kb = 0; kb < 4; ++kb) {
        const int slot = kb * 4 + kq4;
        const int ba = lrow * 256 + ((slot ^ (lrow & 7)) << 4);
        const bf16x8 a = *(const bf16x8*)((const char*)s_bf + ba);
        #pragma unroll
        for (int nt = 0; nt < 8; ++nt) {
            const bf16x8 b = *(const bf16x8*)(e2pk + (((size_t)(kb * 8 + nt) * 64 + l) << 3));
            acc2[nt] = __builtin_amdgcn_mfma_f32_16x16x32_bf16(a, b, acc2[nt], 0, 0, 0);
        }
    }
    #pragma unroll
    for (int nt = 0; nt < 8; ++nt)
        #pragma unroll
        for (int r = 0; r < 4; ++r)
            s_acc[w * 16 + (l >> 4) * 4 + r][nt * 16 + colb] = acc2[nt][r];
    __syncthreads();
    // epilogue2 (row-linear): ea = ea_old + (upd + e2b)/2, vectorized stores
    {
        float* pe = ea + (size_t)er * HD + cg;
        #pragma unroll
        for (int i = 0; i < 8; ++i) {
            const float4 a = *(const float4*)&s_acc[rr][cg + i * 4];
            const float4 b = *(const float4*)&s_b2[cg + i * 4];
            float4 o;
            o.x = eo[i].x + (a.x + b.x) * 0.5f;
            o.y = eo[i].y + (a.y + b.y) * 0.5f;
            o.z = eo[i].z + (a.z + b.z) * 0.5f;
            o.w = eo[i].w + (a.w + b.w) * 0.5f;
            *(float4*)(pe + i * 4) = o;
        }
    }
}

extern "C" void kernel_launch(void* const* d_in, const int* in_sizes, int n_in,
                              void* d_out, int out_size, void* d_ws, size_t ws_size,
                              hipStream_t stream)
{
    const float* x0    = (const float*)d_in[0];
    const float* eatr  = (const float*)d_in[1];
    const float* teatr = (const float*)d_in[2];
    const float* nodeW = (const float*)d_in[3];
    const float* nodeb = (const float*)d_in[4];
    const float* edgeW = (const float*)d_in[5];
    const float* edgeb = (const float*)d_in[6];
    const float* preW  = (const float*)d_in[7];
    const float* preb  = (const float*)d_in[8];
    const float* postW = (const float*)d_in[9];
    const float* postb = (const float*)d_in[10];
    const float* linW  = (const float*)d_in[11];
    const float* linb  = (const float*)d_in[12];
    const float* bng   = (const float*)d_in[13];
    const float* bnb   = (const float*)d_in[14];
    const float* em1W  = (const float*)d_in[15];
    const float* em1b  = (const float*)d_in[16];
    const float* em2W  = (const float*)d_in[17];
    const float* em2b  = (const float*)d_in[18];
    const int*   eidx  = (const int*)d_in[19];
    const int* srcp = eidx;
    const int* dstp = eidx + NE;

    float* out_x  = (float*)d_out;
    float* out_ea = out_x + (size_t)NN * HD;
    float* out_te = out_ea + (size_t)NE * HD;

    const size_t NH = (size_t)NN * HD;
    const size_t EH = (size_t)NE * HD;
    float* xd   = (float*)d_ws;
    float* xs   = xd + NH;
    float* outb = xs + NH;
    float* stats = outb + NH;          // [0]=sum log; [128..255]=bn sum; [256..383]=bn sumsq
    int*   cnt      = (int*)(stats + 512);
    int*   row_start = cnt + NN;       // NN+1
    int*   cursor   = row_start + NN + 1;
    int*   tmpincl  = cursor + NN;
    int*   part     = tmpincl + NN;    // 256
    int*   poff     = part + 256;      // 256
    int*   sppos    = poff + 256;      // NE
    unsigned short* mbuf = (unsigned short*)(((uintptr_t)(sppos + NE) + 15) & ~(uintptr_t)15);
    unsigned short* aggb = mbuf + EH;                  // [NN][512] bf16
    unsigned short* pk   = aggb + (size_t)NN * 512;
    const size_t KBSZ = 512 * 8;   // ushorts per kb
    unsigned short* pkPost = pk;                       // 104 kbs
    unsigned short* pkPre  = pkPost + 104 * KBSZ;      // 24 kbs
    unsigned short* pkEm1  = pkPre  + 24 * KBSZ;       // 24 kbs
    unsigned short* pkLin  = pkEm1  + 24 * KBSZ;       // 8 kbs
    unsigned short* pkEm2  = pkLin  + 8 * KBSZ;        // 8 kbs
    unsigned short* pkNode = pkEm2  + 8 * KBSZ;        // 2 kbs
    unsigned short* pkEdge = pkNode + 2 * KBSZ;        // 1 kb

    hipMemsetAsync(cnt, 0, NN * sizeof(int), stream);
    hipMemsetAsync(stats, 0, 512 * sizeof(float), stream);

    // pack all weights (contiguous k-ranges of each tensor stay contiguous in pack space)
    k_packW<<<208, 256, 0, stream>>>(postW, pkPost, 3328);
    k_packW<<<48, 256, 0, stream>>>(preW,  pkPre,  768);
    k_packW<<<48, 256, 0, stream>>>(em1W,  pkEm1,  768);
    k_packW<<<16, 256, 0, stream>>>(linW,  pkLin,  256);
    k_packW<<<16, 256, 0, stream>>>(em2W,  pkEm2,  256);
    k_packW<<<4, 256, 0, stream>>>(nodeW, pkNode, 64);
    k_packW<<<2, 256, 0, stream>>>(edgeW, pkEdge, 32);

    // prologue embeddings
    k_gemm_mfma<1><<<(NE + 63) / 64, 256, 0, stream>>>(eatr, pkEdge, edgeb, out_ea, NE);
    k_gemm_mfma<1><<<(NTE + 63) / 64, 256, 0, stream>>>(teatr, pkEdge, edgeb, out_te, NTE);
    k_gemm_mfma<2><<<(NN + 63) / 64, 256, 0, stream>>>(x0, pkNode, nodeb, out_x, NN);

    // CSR build
    k_count<<<(NE + 255) / 256, 256, 0, stream>>>(dstp, cnt, NE);
    k_avglog<<<256, 256, 0, stream>>>(cnt, stats);
    k_scan_block<<<SCAN_B, 256, 0, stream>>>(cnt, tmpincl, part);
    k_scan_part<<<1, 256, 0, stream>>>(part, poff, SCAN_B);
    k_scan_add<<<SCAN_B, 256, 0, stream>>>(tmpincl, cnt, poff, row_start, cursor);
    k_scatter<<<(NE + 255) / 256, 256, 0, stream>>>(dstp, cursor, sppos);

    const int gn = (NN + 63) / 64;
    const int ge = NE / 64;

    for (int l = 0; l < NL; ++l) {
        const unsigned short* Wd_pk  = pkPre + (size_t)(l * 12 + 0) * KBSZ;
        const unsigned short* Ws_pk  = pkPre + (size_t)(l * 12 + 4) * KBSZ;
        const unsigned short* We_pk  = pkPre + (size_t)(l * 12 + 8) * KBSZ;
        const unsigned short* W1s_pk = pkEm1 + (size_t)(l * 12 + 0) * KBSZ;
        const unsigned short* W1d_pk = pkEm1 + (size_t)(l * 12 + 4) * KBSZ;
        const unsigned short* W1e_pk = pkEm1 + (size_t)(l * 12 + 8) * KBSZ;
        const unsigned short* PW_pk  = pkPost + (size_t)l * 52 * KBSZ;
        const unsigned short* lin_pk = pkLin + (size_t)l * 4 * KBSZ;
        const unsigned short* em2_pk = pkEm2 + (size_t)l * 4 * KBSZ;
        const float* pbl = preb + l * HD;
        const float* pob = postb + l * HD;
        const float* lb  = linb + l * HD;
        const float* g_  = bng + l * HD;
        const float* b_  = bnb + l * HD;
        const float* e1b = em1b + l * HD;
        const float* e2b = em2b + l * HD;

        hipMemsetAsync(stats + 128, 0, 256 * sizeof(float), stream);

        k_gemm2_mfma<4><<<gn, 256, 0, stream>>>(out_x, Wd_pk, Ws_pk, pbl, xd, xs, NN);
        k_msg_mfma<<<ge, 256, 0, stream>>>(out_ea, We_pk, xs, srcp, sppos, mbuf);
        k_agg<<<(NN + 3) / 4, 256, 0, stream>>>(mbuf, row_start, xd, aggb);
        k_post_lin<<<gn, 256, 0, stream>>>(out_x, aggb, cnt, stats, PW_pk, pob, lin_pk, lb, outb, NN);
        k_bnstats<<<256, 256, 0, stream>>>(outb, stats + 128, stats + 256, NN);
        k_xupdate<<<NN * 32 / 256, 256, 0, stream>>>(out_x, outb, stats + 128, stats + 256, g_, b_);
        k_gemm2_mfma<4><<<gn, 256, 0, stream>>>(out_x, W1d_pk, W1s_pk, e1b, xd, xs, NN);
        k_edge_upd_mfma<<<ge, 256, 0, stream>>>(out_ea, W1e_pk, em2_pk, e2b, xs, xd, srcp, dstp);
    }
}

// Round 6
// 1506.191 us; speedup vs baseline: 1.1029x; 1.1029x over previous
//
#include <hip/hip_runtime.h>
#include <math.h>

#define NN  50000
#define NE  400000
#define NTE 50000
#define FIN 64
#define EDIM 32
#define HD  128
#define NL  2
#define SCAN_B ((NN + 255) / 256)

typedef __attribute__((ext_vector_type(8))) short bf16x8;
typedef __attribute__((ext_vector_type(4))) short bf16x4;
typedef __attribute__((ext_vector_type(4))) float f32x4;

static __device__ __forceinline__ unsigned short f2bf(float f) {
    unsigned u = __float_as_uint(f);
    unsigned r = (u + 0x7fffu + ((u >> 16) & 1u)) >> 16;
    return (unsigned short)r;
}
static __device__ __forceinline__ float bfhi2f(unsigned u) { return __uint_as_float(u & 0xffff0000u); }
static __device__ __forceinline__ float bflo2f(unsigned u) { return __uint_as_float(u << 16); }

static __device__ __forceinline__ bf16x8 load_a8(const float* p, bool ok) {
    bf16x8 a = {};
    if (ok) {
        const float4 v0 = *(const float4*)(p);
        const float4 v1 = *(const float4*)(p + 4);
        a[0] = (short)f2bf(v0.x); a[1] = (short)f2bf(v0.y);
        a[2] = (short)f2bf(v0.z); a[3] = (short)f2bf(v0.w);
        a[4] = (short)f2bf(v1.x); a[5] = (short)f2bf(v1.y);
        a[6] = (short)f2bf(v1.z); a[7] = (short)f2bf(v1.w);
    }
    return a;
}
static __device__ __forceinline__ bf16x8 pack8(float4 a, float4 b) {
    bf16x8 v;
    v[0]=(short)f2bf(a.x); v[1]=(short)f2bf(a.y); v[2]=(short)f2bf(a.z); v[3]=(short)f2bf(a.w);
    v[4]=(short)f2bf(b.x); v[5]=(short)f2bf(b.y); v[6]=(short)f2bf(b.z); v[7]=(short)f2bf(b.w);
    return v;
}
static __device__ __forceinline__ bf16x4 pack4(float4 a) {
    bf16x4 v;
    v[0]=(short)f2bf(a.x); v[1]=(short)f2bf(a.y); v[2]=(short)f2bf(a.z); v[3]=(short)f2bf(a.w);
    return v;
}

// ---- pack fp32 W[K][128] into bf16 MFMA B-frag order: [(kb*8+nt)*64+lane][8] k-contig ----
// (also serves as the A-frag of W^T for the transposed-product kernels)
__global__ void __launch_bounds__(256) k_packW(const float* __restrict__ W,
        unsigned short* __restrict__ out, int K)
{
    const int tid = blockIdx.x * 256 + threadIdx.x;
    const int total = (K / 32) * 512;
    if (tid >= total) return;
    const int lane = tid & 63, nt = (tid >> 6) & 7, kb = tid >> 9;
    const int k0 = kb * 32 + (lane >> 4) * 8;
    const int col = nt * 16 + (lane & 15);
    bf16x8 v;
    #pragma unroll
    for (int j = 0; j < 8; ++j)
        v[j] = (short)f2bf(W[(size_t)(k0 + j) * HD + col]);
    *(bf16x8*)(out + (size_t)tid * 8) = v;
}

// ---- MFMA GEMM (single output, guarded): C = A@W (+bias) ----
template<int KB>
__global__ void __launch_bounds__(256) k_gemm_mfma(const float* A,
        const unsigned short* __restrict__ Wpk, const float* __restrict__ bias,
        float* C, int M)
{
    const int t = threadIdx.x, w = t >> 6, l = t & 63;
    const int row0 = blockIdx.x * 64 + w * 16;
    const int ar = row0 + (l & 15);
    const bool aok = ar < M;
    const int kq = (l >> 4) * 8;
    const int K = KB * 32;
    f32x4 acc[8] = {};
    #pragma unroll
    for (int kb = 0; kb < KB; ++kb) {
        const bf16x8 a = load_a8(A + (size_t)ar * K + kb * 32 + kq, aok);
        #pragma unroll
        for (int nt = 0; nt < 8; ++nt) {
            const bf16x8 b = *(const bf16x8*)(Wpk + (((size_t)(kb * 8 + nt) * 64 + l) << 3));
            acc[nt] = __builtin_amdgcn_mfma_f32_16x16x32_bf16(a, b, acc[nt], 0, 0, 0);
        }
    }
    #pragma unroll
    for (int nt = 0; nt < 8; ++nt) {
        const int col = nt * 16 + (l & 15);
        const float bv = bias ? bias[col] : 0.f;
        #pragma unroll
        for (int r = 0; r < 4; ++r) {
            const int orow = row0 + (l >> 4) * 4 + r;
            if (orow < M) C[(size_t)orow * HD + col] = acc[nt][r] + bv;
        }
    }
}

// ---- MFMA GEMM dual output: C0 = A@W0 + b0, C1 = A@W1 ----
template<int KB>
__global__ void __launch_bounds__(256) k_gemm2_mfma(const float* A,
        const unsigned short* __restrict__ W0, const unsigned short* __restrict__ W1,
        const float* __restrict__ b0, float* C0, float* C1, int M)
{
    const int t = threadIdx.x, w = t >> 6, l = t & 63;
    const int row0 = blockIdx.x * 64 + w * 16;
    const int ar = row0 + (l & 15);
    const bool aok = ar < M;
    const int kq = (l >> 4) * 8;
    const int K = KB * 32;
    f32x4 a0[8] = {}, a1[8] = {};
    #pragma unroll
    for (int kb = 0; kb < KB; ++kb) {
        const bf16x8 a = load_a8(A + (size_t)ar * K + kb * 32 + kq, aok);
        #pragma unroll
        for (int nt = 0; nt < 8; ++nt) {
            const bf16x8 u = *(const bf16x8*)(W0 + (((size_t)(kb * 8 + nt) * 64 + l) << 3));
            const bf16x8 v = *(const bf16x8*)(W1 + (((size_t)(kb * 8 + nt) * 64 + l) << 3));
            a0[nt] = __builtin_amdgcn_mfma_f32_16x16x32_bf16(a, u, a0[nt], 0, 0, 0);
            a1[nt] = __builtin_amdgcn_mfma_f32_16x16x32_bf16(a, v, a1[nt], 0, 0, 0);
        }
    }
    #pragma unroll
    for (int nt = 0; nt < 8; ++nt) {
        const int col = nt * 16 + (l & 15);
        const float bv = b0 ? b0[col] : 0.f;
        #pragma unroll
        for (int r = 0; r < 4; ++r) {
            const int orow = row0 + (l >> 4) * 4 + r;
            if (orow < M) {
                C0[(size_t)orow * HD + col] = a0[nt][r] + bv;
                C1[(size_t)orow * HD + col] = a1[nt][r];
            }
        }
    }
}

// ---- degree count ----
__global__ void __launch_bounds__(256) k_count(const int* __restrict__ d, int* __restrict__ cnt, int E)
{
    const int e = blockIdx.x * 256 + threadIdx.x;
    if (e < E) atomicAdd(&cnt[d[e]], 1);
}

// ---- mean(log(cnt+1)) numerator ----
__global__ void __launch_bounds__(256) k_avglog(const int* __restrict__ cnt, float* __restrict__ stats)
{
    float s = 0.f;
    for (int n = blockIdx.x * 256 + threadIdx.x; n < NN; n += gridDim.x * 256)
        s += logf((float)cnt[n] + 1.f);
    #pragma unroll
    for (int off = 32; off > 0; off >>= 1) s += __shfl_down(s, off);
    __shared__ float ls[4];
    if ((threadIdx.x & 63) == 0) ls[threadIdx.x >> 6] = s;
    __syncthreads();
    if (threadIdx.x == 0) unsafeAtomicAdd(stats, ls[0] + ls[1] + ls[2] + ls[3]);
}

// ---- CSR build ----
__global__ void __launch_bounds__(256) k_scan_block(const int* __restrict__ cnt,
        int* __restrict__ incl, int* __restrict__ part)
{
    __shared__ int s[256];
    const int t = threadIdx.x;
    const int i = blockIdx.x * 256 + t;
    const int v = (i < NN) ? cnt[i] : 0;
    s[t] = v;
    __syncthreads();
    #pragma unroll
    for (int off = 1; off < 256; off <<= 1) {
        const int x = (t >= off) ? s[t - off] : 0;
        __syncthreads();
        s[t] += x;
        __syncthreads();
    }
    if (i < NN) incl[i] = s[t];
    if (t == 255) part[blockIdx.x] = s[255];
}

__global__ void __launch_bounds__(256) k_scan_part(const int* __restrict__ part,
        int* __restrict__ poff, int np)
{
    __shared__ int s[256];
    const int t = threadIdx.x;
    const int v = (t < np) ? part[t] : 0;
    s[t] = v;
    __syncthreads();
    #pragma unroll
    for (int off = 1; off < 256; off <<= 1) {
        const int x = (t >= off) ? s[t - off] : 0;
        __syncthreads();
        s[t] += x;
        __syncthreads();
    }
    poff[t] = s[t] - v;
}

__global__ void __launch_bounds__(256) k_scan_add(const int* __restrict__ incl,
        const int* __restrict__ cnt, const int* __restrict__ poff,
        int* __restrict__ row_start, int* __restrict__ cursor)
{
    const int i = blockIdx.x * 256 + threadIdx.x;
    if (i < NN) {
        const int excl = incl[i] - cnt[i] + poff[blockIdx.x];
        row_start[i] = excl;
        cursor[i] = excl;
    }
    if (i == 0) row_start[NN] = NE;
}

__global__ void __launch_bounds__(256) k_scatter(const int* __restrict__ dstp,
        int* cursor, int* __restrict__ sppos)
{
    const int e = blockIdx.x * 256 + threadIdx.x;
    if (e < NE) sppos[e] = atomicAdd(&cursor[dstp[e]], 1);
}

// ---- transposed msg: m^T = We^T @ ea^T; lane owns one edge, float4-aligned col chunks ----
// m' = ea@We + xs[src]; bf16 row-scatter to mbuf[sppos]. NE % 64 == 0.
__global__ void __launch_bounds__(256) k_msg_T(const float* __restrict__ ea,
        const unsigned short* __restrict__ Wepk, const float* __restrict__ xs,
        const int* __restrict__ srcp, const int* __restrict__ sppos,
        unsigned short* __restrict__ mbuf)
{
    const int t = threadIdx.x, w = t >> 6, l = t & 63;
    const int e = blockIdx.x * 64 + w * 16 + (l & 15);
    const int q = l >> 4, kq = q * 8;
    f32x4 acc[8] = {};
    #pragma unroll
    for (int kb = 0; kb < 4; ++kb) {
        const bf16x8 bea = load_a8(ea + (size_t)e * HD + kb * 32 + kq, true);
        #pragma unroll
        for (int nt = 0; nt < 8; ++nt) {
            const bf16x8 aW = *(const bf16x8*)(Wepk + (((size_t)(kb * 8 + nt) * 64 + l) << 3));
            acc[nt] = __builtin_amdgcn_mfma_f32_16x16x32_bf16(aW, bea, acc[nt], 0, 0, 0);
        }
    }
    const int sn = srcp[e], sp = sppos[e];
    const float* ps = xs + (size_t)sn * HD + q * 4;
    unsigned short* pm = mbuf + (size_t)sp * HD + q * 4;
    #pragma unroll
    for (int nt = 0; nt < 8; ++nt) {
        const float4 sv = *(const float4*)(ps + nt * 16);
        float4 o;
        o.x = acc[nt][0] + sv.x; o.y = acc[nt][1] + sv.y;
        o.z = acc[nt][2] + sv.z; o.w = acc[nt][3] + sv.w;
        *(bf16x4*)(pm + nt * 16) = pack4(o);
    }
}

// ---- CSR aggregation from bf16 m'; shift by xd[n]; bf16 agg out [NN][512] ----
__global__ void __launch_bounds__(256) k_agg(const unsigned short* __restrict__ mbuf,
        const int* __restrict__ rs, const float* __restrict__ xd,
        unsigned short* __restrict__ aggb)
{
    const int n = blockIdx.x * 4 + (threadIdx.x >> 6);
    if (n >= NN) return;
    const int lane = threadIdx.x & 63;
    const int c = lane * 2;
    const int s = rs[n], e = rs[n + 1];
    const float2 xv = *(const float2*)(xd + (size_t)n * HD + c);
    float s0=0.f, s1=0.f, q0=0.f, q1=0.f;
    float mn0=INFINITY, mn1=INFINITY, mx0=-INFINITY, mx1=-INFINITY;
    for (int i = s; i < e; ++i) {
        const unsigned u = *(const unsigned*)(mbuf + (size_t)i * HD + c);
        const float v0 = bflo2f(u), v1 = bfhi2f(u);
        s0 += v0; s1 += v1;
        q0 += v0 * v0; q1 += v1 * v1;
        mn0 = fminf(mn0, v0); mn1 = fminf(mn1, v1);
        mx0 = fmaxf(mx0, v0); mx1 = fmaxf(mx1, v1);
    }
    const int deg = e - s;
    const float inv = 1.f / (float)(deg > 1 ? deg : 1);
    const float fd = (float)deg * inv;          // 0 if deg==0 else 1
    const float m0p = s0 * inv, m1p = s1 * inv;
    const float sd0 = sqrtf(fmaxf(q0 * inv - m0p * m0p, 0.f) + 1e-5f);
    const float sd1 = sqrtf(fmaxf(q1 * inv - m1p * m1p, 0.f) + 1e-5f);
    const bool has = deg > 0;
    const float mean0 = m0p + fd * xv.x, mean1 = m1p + fd * xv.y;
    const float omn0 = has ? mn0 + xv.x : 0.f, omn1 = has ? mn1 + xv.y : 0.f;
    const float omx0 = has ? mx0 + xv.x : 0.f, omx1 = has ? mx1 + xv.y : 0.f;
    unsigned* a = (unsigned*)(aggb + (size_t)n * 512 + c);
    a[0]         = (unsigned)f2bf(mean0) | ((unsigned)f2bf(mean1) << 16);
    *(a + 64)    = (unsigned)f2bf(omn0)  | ((unsigned)f2bf(omn1)  << 16);
    *(a + 128)   = (unsigned)f2bf(omx0)  | ((unsigned)f2bf(omx1)  << 16);
    *(a + 192)   = (unsigned)f2bf(sd0)   | ((unsigned)f2bf(sd1)   << 16);
}

// ---- post fused with lin: out = [x|agg]@PW (amp/att scaled) + pb; outb = out@linW + lb ----
__global__ void __launch_bounds__(256) k_post_lin(const float* __restrict__ x,
        const unsigned short* __restrict__ aggb, const int* __restrict__ cnt,
        const float* __restrict__ stats, const unsigned short* __restrict__ PWpk,
        const float* __restrict__ pb, const unsigned short* __restrict__ LNpk,
        const float* __restrict__ lb, float* __restrict__ outb, int M)
{
    __shared__ float s_amp[64], s_att[64];
    __shared__ unsigned short s_o16[64 * 128];   // swizzled bf16 out tile
    const int t = threadIdx.x;
    const int row0b = blockIdx.x * 64;
    if (t < 64) {
        const int n = row0b + t;
        const float cf = (n < M) ? (float)cnt[n] : 1.f;
        const float avg = stats[0] * (1.f / (float)NN);
        const float lg = logf(fmaxf(cf, 1.f) + 1.f);
        s_amp[t] = lg / avg;
        s_att[t] = avg / lg;
    }
    __syncthreads();
    const int w = t >> 6, l = t & 63;
    const int row0 = row0b + w * 16;
    const int ar = row0 + (l & 15);
    const bool aok = ar < M;
    const int kq = (l >> 4) * 8;
    const int colb = l & 15;
    f32x4 aA[8] = {}, aB[8] = {}, aC[8] = {};

    #pragma unroll
    for (int kb = 0; kb < 4; ++kb) {
        const bf16x8 a = load_a8(x + (size_t)ar * HD + kb * 32 + kq, aok);
        #pragma unroll
        for (int nt = 0; nt < 8; ++nt) {
            const bf16x8 b = *(const bf16x8*)(PWpk + (((size_t)(kb * 8 + nt) * 64 + l) << 3));
            aA[nt] = __builtin_amdgcn_mfma_f32_16x16x32_bf16(a, b, aA[nt], 0, 0, 0);
        }
    }
    for (int jb = 0; jb < 4; ++jb) {
        #pragma unroll
        for (int k2 = 0; k2 < 4; ++k2) {
            bf16x8 a = {};
            if (aok) a = *(const bf16x8*)(aggb + (size_t)ar * 512 + jb * 128 + k2 * 32 + kq);
            const int kb1 = 4  + jb * 4 + k2;
            const int kb2 = 20 + jb * 4 + k2;
            const int kb3 = 36 + jb * 4 + k2;
            #pragma unroll
            for (int nt = 0; nt < 8; ++nt) {
                const bf16x8 b1 = *(const bf16x8*)(PWpk + (((size_t)(kb1 * 8 + nt) * 64 + l) << 3));
                const bf16x8 b2 = *(const bf16x8*)(PWpk + (((size_t)(kb2 * 8 + nt) * 64 + l) << 3));
                const bf16x8 b3 = *(const bf16x8*)(PWpk + (((size_t)(kb3 * 8 + nt) * 64 + l) << 3));
                aA[nt] = __builtin_amdgcn_mfma_f32_16x16x32_bf16(a, b1, aA[nt], 0, 0, 0);
                aB[nt] = __builtin_amdgcn_mfma_f32_16x16x32_bf16(a, b2, aB[nt], 0, 0, 0);
                aC[nt] = __builtin_amdgcn_mfma_f32_16x16x32_bf16(a, b3, aC[nt], 0, 0, 0);
            }
        }
    }
    // out -> swizzled bf16 LDS
    #pragma unroll
    for (int nt = 0; nt < 8; ++nt) {
        const int col = nt * 16 + colb;
        const float bv = pb[col];
        #pragma unroll
        for (int r = 0; r < 4; ++r) {
            const int lr = w * 16 + (l >> 4) * 4 + r;
            const float o = aA[nt][r] + s_amp[lr] * aB[nt][r] + s_att[lr] * aC[nt][r] + bv;
            const int ba = lr * 256 + ((((col >> 3)) ^ (lr & 7)) << 4) + ((col & 7) << 1);
            *(unsigned short*)((char*)s_o16 + ba) = f2bf(o);
        }
    }
    __syncthreads();
    // lin GEMM from LDS
    f32x4 lacc[8] = {};
    const int lrow = w * 16 + (l & 15);
    #pragma unroll
    for (int kb = 0; kb < 4; ++kb) {
        const int slot = kb * 4 + (l >> 4);
        const int ba = lrow * 256 + ((slot ^ (lrow & 7)) << 4);
        const bf16x8 a = *(const bf16x8*)((const char*)s_o16 + ba);
        #pragma unroll
        for (int nt = 0; nt < 8; ++nt) {
            const bf16x8 b = *(const bf16x8*)(LNpk + (((size_t)(kb * 8 + nt) * 64 + l) << 3));
            lacc[nt] = __builtin_amdgcn_mfma_f32_16x16x32_bf16(a, b, lacc[nt], 0, 0, 0);
        }
    }
    #pragma unroll
    for (int nt = 0; nt < 8; ++nt) {
        const int col = nt * 16 + colb;
        const float bv = lb[col];
        #pragma unroll
        for (int r = 0; r < 4; ++r) {
            const int orow = row0b + w * 16 + (l >> 4) * 4 + r;
            if (orow < M) outb[(size_t)orow * HD + col] = lacc[nt][r] + bv;
        }
    }
}

// ---- BN column sums ----
__global__ void __launch_bounds__(256) k_bnstats(const float* __restrict__ ob,
        float* __restrict__ bs, float* __restrict__ bq, int M)
{
    const int c = threadIdx.x & 127;
    const int gsub = threadIdx.x >> 7;
    float s = 0.f, qq = 0.f;
    for (int rr = blockIdx.x * 2 + gsub; rr < M; rr += gridDim.x * 2) {
        const float v = ob[(size_t)rr * HD + c];
        s += v; qq += v * v;
    }
    __shared__ float ls[2][HD], lq[2][HD];
    ls[gsub][c] = s; lq[gsub][c] = qq;
    __syncthreads();
    if (gsub == 0) {
        unsafeAtomicAdd(&bs[c], ls[0][c] + ls[1][c]);
        unsafeAtomicAdd(&bq[c], lq[0][c] + lq[1][c]);
    }
}

// ---- x = (x + relu(bn(out)))/2 ----
__global__ void __launch_bounds__(256) k_xupdate(float* x, const float* __restrict__ ob,
        const float* __restrict__ bs, const float* __restrict__ bq,
        const float* __restrict__ g, const float* __restrict__ bb)
{
    const int i = blockIdx.x * 256 + threadIdx.x;
    const int c0 = (i & 31) * 4;
    const float4 ov = ((const float4*)ob)[i];
    const float4 xv = ((const float4*)x)[i];
    const float o[4]  = {ov.x, ov.y, ov.z, ov.w};
    const float xo[4] = {xv.x, xv.y, xv.z, xv.w};
    float res[4];
    #pragma unroll
    for (int j = 0; j < 4; ++j) {
        const int c = c0 + j;
        const float mu  = bs[c] * (1.f / (float)NN);
        const float var = bq[c] * (1.f / (float)NN) - mu * mu;
        const float bn  = g[c] * (o[j] - mu) * rsqrtf(var + 1e-5f) + bb[c];
        res[j] = (xo[j] + fmaxf(bn, 0.f)) * 0.5f;
    }
    ((float4*)x)[i] = make_float4(res[0], res[1], res[2], res[3]);
}

// ---- transposed edge update: hid^T = W1e^T@ea^T (+gathers, relu) -> bf16 LDS;
//      upd^T = em2^T@hid^T; ea += (upd + e2b)/2. One barrier, vector epilogues. ----
__global__ void __launch_bounds__(256) k_edge_upd_T(float* ea,
        const unsigned short* __restrict__ W1epk, const unsigned short* __restrict__ e2pk,
        const float* __restrict__ e2b, const float* __restrict__ xs1,
        const float* __restrict__ xd1, const int* __restrict__ srcp,
        const int* __restrict__ dstp)
{
    __shared__ unsigned short s_hid[64 * 128];   // bf16, 16B-slot XOR swizzled
    __shared__ float s_b2[128];
    const int t = threadIdx.x, w = t >> 6, l = t & 63;
    const int row0b = blockIdx.x * 64;
    if (t < 128) s_b2[t] = e2b[t];
    const int el = w * 16 + (l & 15);            // local edge row 0..63 (wave-local 16)
    const int e = row0b + el;
    const int q = l >> 4, kq = q * 8;
    // GEMM1 (transposed): acc1[nt] = W1e^T @ ea^T
    f32x4 acc1[8] = {};
    #pragma unroll
    for (int kb = 0; kb < 4; ++kb) {
        const bf16x8 bea = load_a8(ea + (size_t)e * HD + kb * 32 + kq, true);
        #pragma unroll
        for (int nt = 0; nt < 8; ++nt) {
            const bf16x8 aW = *(const bf16x8*)(W1epk + (((size_t)(kb * 8 + nt) * 64 + l) << 3));
            acc1[nt] = __builtin_amdgcn_mfma_f32_16x16x32_bf16(aW, bea, acc1[nt], 0, 0, 0);
        }
    }
    // epilogue1 in regs: hid = relu(acc1 + xs1[src] + xd1[dst]) at cols nt*16 + q*4 -> LDS
    {
        const int sn = srcp[e], dn = dstp[e];
        const float* ps = xs1 + (size_t)sn * HD + q * 4;
        const float* pd = xd1 + (size_t)dn * HD + q * 4;
        #pragma unroll
        for (int nt = 0; nt < 8; ++nt) {
            const float4 sv = *(const float4*)(ps + nt * 16);
            const float4 dv = *(const float4*)(pd + nt * 16);
            float4 h;
            h.x = fmaxf(acc1[nt][0] + sv.x + dv.x, 0.f);
            h.y = fmaxf(acc1[nt][1] + sv.y + dv.y, 0.f);
            h.z = fmaxf(acc1[nt][2] + sv.z + dv.z, 0.f);
            h.w = fmaxf(acc1[nt][3] + sv.w + dv.w, 0.f);
            const int bcol = nt * 32 + q * 8;                 // byte col of col*2
            const int slot = bcol >> 4;
            const int ba = el * 256 + ((slot ^ (el & 7)) << 4) + (bcol & 15);
            *(bf16x4*)((char*)s_hid + ba) = pack4(h);
        }
    }
    __syncthreads();
    // GEMM2 (transposed): acc2 = em2^T @ hid^T; B-frag = hid[e][kq'+j] from LDS
    f32x4 acc2[8] = {};
    #pragma unroll
    for (int kb = 0; kb < 4; ++kb) {
        const int slot = kb * 4 + q;
        const int ba = el * 256 + ((slot ^ (el & 7)) << 4);
        const bf16x8 bh = *(const bf16x8*)((const char*)s_hid + ba);
        #pragma unroll
        for (int nt = 0; nt < 8; ++nt) {
            const bf16x8 aW = *(const bf16x8*)(e2pk + (((size_t)(kb * 8 + nt) * 64 + l) << 3));
            acc2[nt] = __builtin_amdgcn_mfma_f32_16x16x32_bf16(aW, bh, acc2[nt], 0, 0, 0);
        }
    }
    // epilogue2 in regs: ea = ea_old + (acc2 + e2b)/2, float4 ops
    {
        float* pe = ea + (size_t)e * HD + q * 4;
        #pragma unroll
        for (int nt = 0; nt < 8; ++nt) {
            const float4 eo = *(const float4*)(pe + nt * 16);
            const float4 bv = *(const float4*)(&s_b2[nt * 16 + q * 4]);
            float4 o;
            o.x = eo.x + (acc2[nt][0] + bv.x) * 0.5f;
            o.y = eo.y + (acc2[nt][1] + bv.y) * 0.5f;
            o.z = eo.z + (acc2[nt][2] + bv.z) * 0.5f;
            o.w = eo.w + (acc2[nt][3] + bv.w) * 0.5f;
            *(float4*)(pe + nt * 16) = o;
        }
    }
}

extern "C" void kernel_launch(void* const* d_in, const int* in_sizes, int n_in,
                              void* d_out, int out_size, void* d_ws, size_t ws_size,
                              hipStream_t stream)
{
    const float* x0    = (const float*)d_in[0];
    const float* eatr  = (const float*)d_in[1];
    const float* teatr = (const float*)d_in[2];
    const float* nodeW = (const float*)d_in[3];
    const float* nodeb = (const float*)d_in[4];
    const float* edgeW = (const float*)d_in[5];
    const float* edgeb = (const float*)d_in[6];
    const float* preW  = (const float*)d_in[7];
    const float* preb  = (const float*)d_in[8];
    const float* postW = (const float*)d_in[9];
    const float* postb = (const float*)d_in[10];
    const float* linW  = (const float*)d_in[11];
    const float* linb  = (const float*)d_in[12];
    const float* bng   = (const float*)d_in[13];
    const float* bnb   = (const float*)d_in[14];
    const float* em1W  = (const float*)d_in[15];
    const float* em1b  = (const float*)d_in[16];
    const float* em2W  = (const float*)d_in[17];
    const float* em2b  = (const float*)d_in[18];
    const int*   eidx  = (const int*)d_in[19];
    const int* srcp = eidx;
    const int* dstp = eidx + NE;

    float* out_x  = (float*)d_out;
    float* out_ea = out_x + (size_t)NN * HD;
    float* out_te = out_ea + (size_t)NE * HD;

    const size_t NH = (size_t)NN * HD;
    const size_t EH = (size_t)NE * HD;
    float* xd   = (float*)d_ws;
    float* xs   = xd + NH;
    float* outb = xs + NH;
    float* stats = outb + NH;          // [0]=sum log; [128..255]=bn sum; [256..383]=bn sumsq
    int*   cnt      = (int*)(stats + 512);
    int*   row_start = cnt + NN;       // NN+1
    int*   cursor   = row_start + NN + 1;
    int*   tmpincl  = cursor + NN;
    int*   part     = tmpincl + NN;    // 256
    int*   poff     = part + 256;      // 256
    int*   sppos    = poff + 256;      // NE
    unsigned short* mbuf = (unsigned short*)(((uintptr_t)(sppos + NE) + 15) & ~(uintptr_t)15);
    unsigned short* aggb = mbuf + EH;                  // [NN][512] bf16
    unsigned short* pk   = aggb + (size_t)NN * 512;
    const size_t KBSZ = 512 * 8;   // ushorts per kb
    unsigned short* pkPost = pk;                       // 104 kbs
    unsigned short* pkPre  = pkPost + 104 * KBSZ;      // 24 kbs
    unsigned short* pkEm1  = pkPre  + 24 * KBSZ;       // 24 kbs
    unsigned short* pkLin  = pkEm1  + 24 * KBSZ;       // 8 kbs
    unsigned short* pkEm2  = pkLin  + 8 * KBSZ;        // 8 kbs
    unsigned short* pkNode = pkEm2  + 8 * KBSZ;        // 2 kbs
    unsigned short* pkEdge = pkNode + 2 * KBSZ;        // 1 kb

    hipMemsetAsync(cnt, 0, NN * sizeof(int), stream);
    hipMemsetAsync(stats, 0, 512 * sizeof(float), stream);

    // pack all weights
    k_packW<<<208, 256, 0, stream>>>(postW, pkPost, 3328);
    k_packW<<<48, 256, 0, stream>>>(preW,  pkPre,  768);
    k_packW<<<48, 256, 0, stream>>>(em1W,  pkEm1,  768);
    k_packW<<<16, 256, 0, stream>>>(linW,  pkLin,  256);
    k_packW<<<16, 256, 0, stream>>>(em2W,  pkEm2,  256);
    k_packW<<<4, 256, 0, stream>>>(nodeW, pkNode, 64);
    k_packW<<<2, 256, 0, stream>>>(edgeW, pkEdge, 32);

    // prologue embeddings
    k_gemm_mfma<1><<<(NE + 63) / 64, 256, 0, stream>>>(eatr, pkEdge, edgeb, out_ea, NE);
    k_gemm_mfma<1><<<(NTE + 63) / 64, 256, 0, stream>>>(teatr, pkEdge, edgeb, out_te, NTE);
    k_gemm_mfma<2><<<(NN + 63) / 64, 256, 0, stream>>>(x0, pkNode, nodeb, out_x, NN);

    // CSR build
    k_count<<<(NE + 255) / 256, 256, 0, stream>>>(dstp, cnt, NE);
    k_avglog<<<256, 256, 0, stream>>>(cnt, stats);
    k_scan_block<<<SCAN_B, 256, 0, stream>>>(cnt, tmpincl, part);
    k_scan_part<<<1, 256, 0, stream>>>(part, poff, SCAN_B);
    k_scan_add<<<SCAN_B, 256, 0, stream>>>(tmpincl, cnt, poff, row_start, cursor);
    k_scatter<<<(NE + 255) / 256, 256, 0, stream>>>(dstp, cursor, sppos);

    const int gn = (NN + 63) / 64;
    const int ge = NE / 64;

    for (int l = 0; l < NL; ++l) {
        const unsigned short* Wd_pk  = pkPre + (size_t)(l * 12 + 0) * KBSZ;
        const unsigned short* Ws_pk  = pkPre + (size_t)(l * 12 + 4) * KBSZ;
        const unsigned short* We_pk  = pkPre + (size_t)(l * 12 + 8) * KBSZ;
        const unsigned short* W1s_pk = pkEm1 + (size_t)(l * 12 + 0) * KBSZ;
        const unsigned short* W1d_pk = pkEm1 + (size_t)(l * 12 + 4) * KBSZ;
        const unsigned short* W1e_pk = pkEm1 + (size_t)(l * 12 + 8) * KBSZ;
        const unsigned short* PW_pk  = pkPost + (size_t)l * 52 * KBSZ;
        const unsigned short* lin_pk = pkLin + (size_t)l * 4 * KBSZ;
        const unsigned short* em2_pk = pkEm2 + (size_t)l * 4 * KBSZ;
        const float* pbl = preb + l * HD;
        const float* pob = postb + l * HD;
        const float* lb  = linb + l * HD;
        const float* g_  = bng + l * HD;
        const float* b_  = bnb + l * HD;
        const float* e1b = em1b + l * HD;
        const float* e2b = em2b + l * HD;

        hipMemsetAsync(stats + 128, 0, 256 * sizeof(float), stream);

        k_gemm2_mfma<4><<<gn, 256, 0, stream>>>(out_x, Wd_pk, Ws_pk, pbl, xd, xs, NN);
        k_msg_T<<<ge, 256, 0, stream>>>(out_ea, We_pk, xs, srcp, sppos, mbuf);
        k_agg<<<(NN + 3) / 4, 256, 0, stream>>>(mbuf, row_start, xd, aggb);
        k_post_lin<<<gn, 256, 0, stream>>>(out_x, aggb, cnt, stats, PW_pk, pob, lin_pk, lb, outb, NN);
        k_bnstats<<<256, 256, 0, stream>>>(outb, stats + 128, stats + 256, NN);
        k_xupdate<<<NN * 32 / 256, 256, 0, stream>>>(out_x, outb, stats + 128, stats + 256, g_, b_);
        k_gemm2_mfma<4><<<gn, 256, 0, stream>>>(out_x, W1d_pk, W1s_pk, e1b, xd, xs, NN);
        k_edge_upd_T<<<ge, 256, 0, stream>>>(out_ea, W1e_pk, em2_pk, e2b, xs, xd, srcp, dstp);
    }
}

// Round 7
// 1453.519 us; speedup vs baseline: 1.1429x; 1.0362x over previous
//
#include <hip/hip_runtime.h>
#include <math.h>

#define NN  50000
#define NE  400000
#define NTE 50000
#define FIN 64
#define EDIM 32
#define HD  128
#define NL  2
#define SCAN_B ((NN + 255) / 256)

typedef __attribute__((ext_vector_type(8))) short bf16x8;
typedef __attribute__((ext_vector_type(4))) short bf16x4;
typedef __attribute__((ext_vector_type(4))) float f32x4;

static __device__ __forceinline__ unsigned short f2bf(float f) {
    unsigned u = __float_as_uint(f);
    unsigned r = (u + 0x7fffu + ((u >> 16) & 1u)) >> 16;
    return (unsigned short)r;
}
static __device__ __forceinline__ float bfhi2f(unsigned u) { return __uint_as_float(u & 0xffff0000u); }
static __device__ __forceinline__ float bflo2f(unsigned u) { return __uint_as_float(u << 16); }

static __device__ __forceinline__ bf16x8 load_a8(const float* p, bool ok) {
    bf16x8 a = {};
    if (ok) {
        const float4 v0 = *(const float4*)(p);
        const float4 v1 = *(const float4*)(p + 4);
        a[0] = (short)f2bf(v0.x); a[1] = (short)f2bf(v0.y);
        a[2] = (short)f2bf(v0.z); a[3] = (short)f2bf(v0.w);
        a[4] = (short)f2bf(v1.x); a[5] = (short)f2bf(v1.y);
        a[6] = (short)f2bf(v1.z); a[7] = (short)f2bf(v1.w);
    }
    return a;
}
static __device__ __forceinline__ bf16x4 pack4(float4 a) {
    bf16x4 v;
    v[0]=(short)f2bf(a.x); v[1]=(short)f2bf(a.y); v[2]=(short)f2bf(a.z); v[3]=(short)f2bf(a.w);
    return v;
}

// ---- pack fp32 W[K][128] into bf16 MFMA frag order: [(kb*8+nt)*64+lane][8] k-contig ----
// serves as B-frag of W (row-product) AND A-frag of W^T (transposed product)
__global__ void __launch_bounds__(256) k_packW(const float* __restrict__ W,
        unsigned short* __restrict__ out, int K)
{
    const int tid = blockIdx.x * 256 + threadIdx.x;
    const int total = (K / 32) * 512;
    if (tid >= total) return;
    const int lane = tid & 63, nt = (tid >> 6) & 7, kb = tid >> 9;
    const int k0 = kb * 32 + (lane >> 4) * 8;
    const int col = nt * 16 + (lane & 15);
    bf16x8 v;
    #pragma unroll
    for (int j = 0; j < 8; ++j)
        v[j] = (short)f2bf(W[(size_t)(k0 + j) * HD + col]);
    *(bf16x8*)(out + (size_t)tid * 8) = v;
}

// ---- transposed MFMA GEMM: C = A@W (+bias); lane owns one row, float4 stores ----
template<int KB>
__global__ void __launch_bounds__(256) k_gemm_T(const float* A,
        const unsigned short* __restrict__ Wpk, const float* __restrict__ bias,
        float* C, int M)
{
    const int t = threadIdx.x, w = t >> 6, l = t & 63;
    const int n = blockIdx.x * 64 + w * 16 + (l & 15);
    const bool ok = n < M;
    const int q = l >> 4;
    const int K = KB * 32;
    f32x4 acc[8] = {};
    #pragma unroll
    for (int kb = 0; kb < KB; ++kb) {
        const bf16x8 b = load_a8(A + (size_t)n * K + kb * 32 + q * 8, ok);
        #pragma unroll
        for (int nt = 0; nt < 8; ++nt) {
            const bf16x8 aW = *(const bf16x8*)(Wpk + (((size_t)(kb * 8 + nt) * 64 + l) << 3));
            acc[nt] = __builtin_amdgcn_mfma_f32_16x16x32_bf16(aW, b, acc[nt], 0, 0, 0);
        }
    }
    if (ok) {
        float* pc = C + (size_t)n * HD + q * 4;
        #pragma unroll
        for (int nt = 0; nt < 8; ++nt) {
            const int col = nt * 16 + q * 4;
            float4 bv = bias ? *(const float4*)(bias + col) : make_float4(0.f,0.f,0.f,0.f);
            float4 o;
            o.x = acc[nt][0] + bv.x; o.y = acc[nt][1] + bv.y;
            o.z = acc[nt][2] + bv.z; o.w = acc[nt][3] + bv.w;
            *(float4*)(pc + nt * 16) = o;
        }
    }
}

// ---- transposed dual GEMM: C0 = A@W0 + b0, C1 = A@W1 ----
template<int KB>
__global__ void __launch_bounds__(256) k_gemm2_T(const float* A,
        const unsigned short* __restrict__ W0, const unsigned short* __restrict__ W1,
        const float* __restrict__ b0, float* C0, float* C1, int M)
{
    const int t = threadIdx.x, w = t >> 6, l = t & 63;
    const int n = blockIdx.x * 64 + w * 16 + (l & 15);
    const bool ok = n < M;
    const int q = l >> 4;
    const int K = KB * 32;
    f32x4 a0[8] = {}, a1[8] = {};
    #pragma unroll
    for (int kb = 0; kb < KB; ++kb) {
        const bf16x8 b = load_a8(A + (size_t)n * K + kb * 32 + q * 8, ok);
        #pragma unroll
        for (int nt = 0; nt < 8; ++nt) {
            const bf16x8 u = *(const bf16x8*)(W0 + (((size_t)(kb * 8 + nt) * 64 + l) << 3));
            const bf16x8 v = *(const bf16x8*)(W1 + (((size_t)(kb * 8 + nt) * 64 + l) << 3));
            a0[nt] = __builtin_amdgcn_mfma_f32_16x16x32_bf16(u, b, a0[nt], 0, 0, 0);
            a1[nt] = __builtin_amdgcn_mfma_f32_16x16x32_bf16(v, b, a1[nt], 0, 0, 0);
        }
    }
    if (ok) {
        float* p0 = C0 + (size_t)n * HD + q * 4;
        float* p1 = C1 + (size_t)n * HD + q * 4;
        #pragma unroll
        for (int nt = 0; nt < 8; ++nt) {
            const int col = nt * 16 + q * 4;
            float4 bv = b0 ? *(const float4*)(b0 + col) : make_float4(0.f,0.f,0.f,0.f);
            float4 o0, o1;
            o0.x = a0[nt][0] + bv.x; o0.y = a0[nt][1] + bv.y;
            o0.z = a0[nt][2] + bv.z; o0.w = a0[nt][3] + bv.w;
            o1.x = a1[nt][0]; o1.y = a1[nt][1]; o1.z = a1[nt][2]; o1.w = a1[nt][3];
            *(float4*)(p0 + nt * 16) = o0;
            *(float4*)(p1 + nt * 16) = o1;
        }
    }
}

// ---- degree count ----
__global__ void __launch_bounds__(256) k_count(const int* __restrict__ d, int* __restrict__ cnt, int E)
{
    const int e = blockIdx.x * 256 + threadIdx.x;
    if (e < E) atomicAdd(&cnt[d[e]], 1);
}

// ---- mean(log(cnt+1)) numerator ----
__global__ void __launch_bounds__(256) k_avglog(const int* __restrict__ cnt, float* __restrict__ stats)
{
    float s = 0.f;
    for (int n = blockIdx.x * 256 + threadIdx.x; n < NN; n += gridDim.x * 256)
        s += logf((float)cnt[n] + 1.f);
    #pragma unroll
    for (int off = 32; off > 0; off >>= 1) s += __shfl_down(s, off);
    __shared__ float ls[4];
    if ((threadIdx.x & 63) == 0) ls[threadIdx.x >> 6] = s;
    __syncthreads();
    if (threadIdx.x == 0) unsafeAtomicAdd(stats, ls[0] + ls[1] + ls[2] + ls[3]);
}

// ---- CSR build ----
__global__ void __launch_bounds__(256) k_scan_block(const int* __restrict__ cnt,
        int* __restrict__ incl, int* __restrict__ part)
{
    __shared__ int s[256];
    const int t = threadIdx.x;
    const int i = blockIdx.x * 256 + t;
    const int v = (i < NN) ? cnt[i] : 0;
    s[t] = v;
    __syncthreads();
    #pragma unroll
    for (int off = 1; off < 256; off <<= 1) {
        const int x = (t >= off) ? s[t - off] : 0;
        __syncthreads();
        s[t] += x;
        __syncthreads();
    }
    if (i < NN) incl[i] = s[t];
    if (t == 255) part[blockIdx.x] = s[255];
}

__global__ void __launch_bounds__(256) k_scan_part(const int* __restrict__ part,
        int* __restrict__ poff, int np)
{
    __shared__ int s[256];
    const int t = threadIdx.x;
    const int v = (t < np) ? part[t] : 0;
    s[t] = v;
    __syncthreads();
    #pragma unroll
    for (int off = 1; off < 256; off <<= 1) {
        const int x = (t >= off) ? s[t - off] : 0;
        __syncthreads();
        s[t] += x;
        __syncthreads();
    }
    poff[t] = s[t] - v;
}

__global__ void __launch_bounds__(256) k_scan_add(const int* __restrict__ incl,
        const int* __restrict__ cnt, const int* __restrict__ poff,
        int* __restrict__ row_start, int* __restrict__ cursor)
{
    const int i = blockIdx.x * 256 + threadIdx.x;
    if (i < NN) {
        const int excl = incl[i] - cnt[i] + poff[blockIdx.x];
        row_start[i] = excl;
        cursor[i] = excl;
    }
    if (i == 0) row_start[NN] = NE;
}

__global__ void __launch_bounds__(256) k_scatter(const int* __restrict__ dstp,
        int* cursor, int* __restrict__ sppos)
{
    const int e = blockIdx.x * 256 + threadIdx.x;
    if (e < NE) sppos[e] = atomicAdd(&cursor[dstp[e]], 1);
}

// ---- transposed msg: m' = ea@We + xs[src]; bf16 row-scatter to mbuf[sppos] ----
__global__ void __launch_bounds__(256) k_msg_T(const float* __restrict__ ea,
        const unsigned short* __restrict__ Wepk, const float* __restrict__ xs,
        const int* __restrict__ srcp, const int* __restrict__ sppos,
        unsigned short* __restrict__ mbuf)
{
    const int t = threadIdx.x, w = t >> 6, l = t & 63;
    const int e = blockIdx.x * 64 + w * 16 + (l & 15);
    const int q = l >> 4, kq = q * 8;
    f32x4 acc[8] = {};
    #pragma unroll
    for (int kb = 0; kb < 4; ++kb) {
        const bf16x8 bea = load_a8(ea + (size_t)e * HD + kb * 32 + kq, true);
        #pragma unroll
        for (int nt = 0; nt < 8; ++nt) {
            const bf16x8 aW = *(const bf16x8*)(Wepk + (((size_t)(kb * 8 + nt) * 64 + l) << 3));
            acc[nt] = __builtin_amdgcn_mfma_f32_16x16x32_bf16(aW, bea, acc[nt], 0, 0, 0);
        }
    }
    const int sn = srcp[e], sp = sppos[e];
    const float* ps = xs + (size_t)sn * HD + q * 4;
    unsigned short* pm = mbuf + (size_t)sp * HD + q * 4;
    #pragma unroll
    for (int nt = 0; nt < 8; ++nt) {
        const float4 sv = *(const float4*)(ps + nt * 16);
        float4 o;
        o.x = acc[nt][0] + sv.x; o.y = acc[nt][1] + sv.y;
        o.z = acc[nt][2] + sv.z; o.w = acc[nt][3] + sv.w;
        *(bf16x4*)(pm + nt * 16) = pack4(o);
    }
}

// ---- CSR aggregation; shift by xd[n]; writes [agg | agg*amp | agg*att] bf16 [NN][1536] ----
__global__ void __launch_bounds__(256) k_agg(const unsigned short* __restrict__ mbuf,
        const int* __restrict__ rs, const float* __restrict__ xd,
        const float* __restrict__ stats, unsigned short* __restrict__ aggb)
{
    const int n = blockIdx.x * 4 + (threadIdx.x >> 6);
    if (n >= NN) return;
    const int lane = threadIdx.x & 63;
    const int c = lane * 2;
    const int s = rs[n], e = rs[n + 1];
    const float2 xv = *(const float2*)(xd + (size_t)n * HD + c);
    float s0=0.f, s1=0.f, q0=0.f, q1=0.f;
    float mn0=INFINITY, mn1=INFINITY, mx0=-INFINITY, mx1=-INFINITY;
    for (int i = s; i < e; ++i) {
        const unsigned u = *(const unsigned*)(mbuf + (size_t)i * HD + c);
        const float v0 = bflo2f(u), v1 = bfhi2f(u);
        s0 += v0; s1 += v1;
        q0 += v0 * v0; q1 += v1 * v1;
        mn0 = fminf(mn0, v0); mn1 = fminf(mn1, v1);
        mx0 = fmaxf(mx0, v0); mx1 = fmaxf(mx1, v1);
    }
    const int deg = e - s;
    const float inv = 1.f / (float)(deg > 1 ? deg : 1);
    const float fd = (float)deg * inv;          // 0 if deg==0 else 1
    const float m0p = s0 * inv, m1p = s1 * inv;
    const float sd0 = sqrtf(fmaxf(q0 * inv - m0p * m0p, 0.f) + 1e-5f);
    const float sd1 = sqrtf(fmaxf(q1 * inv - m1p * m1p, 0.f) + 1e-5f);
    const bool has = deg > 0;
    const float v0[4] = { m0p + fd * xv.x, has ? mn0 + xv.x : 0.f,
                          has ? mx0 + xv.x : 0.f, sd0 };
    const float v1[4] = { m1p + fd * xv.y, has ? mn1 + xv.y : 0.f,
                          has ? mx1 + xv.y : 0.f, sd1 };
    const float avg = stats[0] * (1.f / (float)NN);
    const float lg = logf(fmaxf((float)deg, 1.f) + 1.f);
    const float amp = lg / avg, att = avg / lg;
    unsigned* a = (unsigned*)(aggb + (size_t)n * 1536 + c);
    #pragma unroll
    for (int sct = 0; sct < 4; ++sct) {
        a[sct * 64]       = (unsigned)f2bf(v0[sct])       | ((unsigned)f2bf(v1[sct]) << 16);
        a[256 + sct * 64] = (unsigned)f2bf(v0[sct] * amp) | ((unsigned)f2bf(v1[sct] * amp) << 16);
        a[512 + sct * 64] = (unsigned)f2bf(v0[sct] * att) | ((unsigned)f2bf(v1[sct] * att) << 16);
    }
}

// ---- transposed post+lin: out = [x|agg3]@PW + pb (K=1664, ONE acc set); outb = out@linW + lb ----
__global__ void __launch_bounds__(256) k_post_lin_T(const float* __restrict__ x,
        const unsigned short* __restrict__ aggb, const unsigned short* __restrict__ PWpk,
        const float* __restrict__ pb, const unsigned short* __restrict__ LNpk,
        const float* __restrict__ lb, float* __restrict__ outb, int M)
{
    __shared__ unsigned short s_o16[64 * 128];   // swizzled bf16 out tile
    const int t = threadIdx.x, w = t >> 6, l = t & 63;
    const int el = w * 16 + (l & 15);
    const int n = blockIdx.x * 64 + el;
    const bool ok = n < M;
    const int q = l >> 4;
    f32x4 acc[8] = {};
    // x region (kb 0..3)
    #pragma unroll
    for (int kb = 0; kb < 4; ++kb) {
        const bf16x8 b = load_a8(x + (size_t)n * HD + kb * 32 + q * 8, ok);
        #pragma unroll
        for (int nt = 0; nt < 8; ++nt) {
            const bf16x8 aW = *(const bf16x8*)(PWpk + (((size_t)(kb * 8 + nt) * 64 + l) << 3));
            acc[nt] = __builtin_amdgcn_mfma_f32_16x16x32_bf16(aW, b, acc[nt], 0, 0, 0);
        }
    }
    // agg3 region (kb 4..51): B-frags loaded directly as bf16
    const unsigned short* arow = aggb + (size_t)n * 1536 + q * 8;
    #pragma unroll 4
    for (int kb = 4; kb < 52; ++kb) {
        bf16x8 b = {};
        if (ok) b = *(const bf16x8*)(arow + (size_t)(kb - 4) * 32);
        #pragma unroll
        for (int nt = 0; nt < 8; ++nt) {
            const bf16x8 aW = *(const bf16x8*)(PWpk + (((size_t)(kb * 8 + nt) * 64 + l) << 3));
            acc[nt] = __builtin_amdgcn_mfma_f32_16x16x32_bf16(aW, b, acc[nt], 0, 0, 0);
        }
    }
    // epilogue1: + pb -> swizzled bf16 LDS
    #pragma unroll
    for (int nt = 0; nt < 8; ++nt) {
        const int col = nt * 16 + q * 4;
        const float4 bv = *(const float4*)(pb + col);
        float4 o;
        o.x = acc[nt][0] + bv.x; o.y = acc[nt][1] + bv.y;
        o.z = acc[nt][2] + bv.z; o.w = acc[nt][3] + bv.w;
        const int bcol = nt * 32 + q * 8;
        const int slot = bcol >> 4;
        const int ba = el * 256 + ((slot ^ (el & 7)) << 4) + (bcol & 15);
        *(bf16x4*)((char*)s_o16 + ba) = pack4(o);
    }
    __syncthreads();
    // lin GEMM (transposed) from LDS
    f32x4 acc2[8] = {};
    #pragma unroll
    for (int kb = 0; kb < 4; ++kb) {
        const int slot = kb * 4 + q;
        const int ba = el * 256 + ((slot ^ (el & 7)) << 4);
        const bf16x8 bh = *(const bf16x8*)((const char*)s_o16 + ba);
        #pragma unroll
        for (int nt = 0; nt < 8; ++nt) {
            const bf16x8 aW = *(const bf16x8*)(LNpk + (((size_t)(kb * 8 + nt) * 64 + l) << 3));
            acc2[nt] = __builtin_amdgcn_mfma_f32_16x16x32_bf16(aW, bh, acc2[nt], 0, 0, 0);
        }
    }
    if (ok) {
        float* pc = outb + (size_t)n * HD + q * 4;
        #pragma unroll
        for (int nt = 0; nt < 8; ++nt) {
            const int col = nt * 16 + q * 4;
            const float4 bv = *(const float4*)(lb + col);
            float4 o;
            o.x = acc2[nt][0] + bv.x; o.y = acc2[nt][1] + bv.y;
            o.z = acc2[nt][2] + bv.z; o.w = acc2[nt][3] + bv.w;
            *(float4*)(pc + nt * 16) = o;
        }
    }
}

// ---- BN column sums ----
__global__ void __launch_bounds__(256) k_bnstats(const float* __restrict__ ob,
        float* __restrict__ bs, float* __restrict__ bq, int M)
{
    const int c = threadIdx.x & 127;
    const int gsub = threadIdx.x >> 7;
    float s = 0.f, qq = 0.f;
    for (int rr = blockIdx.x * 2 + gsub; rr < M; rr += gridDim.x * 2) {
        const float v = ob[(size_t)rr * HD + c];
        s += v; qq += v * v;
    }
    __shared__ float ls[2][HD], lq[2][HD];
    ls[gsub][c] = s; lq[gsub][c] = qq;
    __syncthreads();
    if (gsub == 0) {
        unsafeAtomicAdd(&bs[c], ls[0][c] + ls[1][c]);
        unsafeAtomicAdd(&bq[c], lq[0][c] + lq[1][c]);
    }
}

// ---- x = (x + relu(bn(out)))/2 ----
__global__ void __launch_bounds__(256) k_xupdate(float* x, const float* __restrict__ ob,
        const float* __restrict__ bs, const float* __restrict__ bq,
        const float* __restrict__ g, const float* __restrict__ bb)
{
    const int i = blockIdx.x * 256 + threadIdx.x;
    const int c0 = (i & 31) * 4;
    const float4 ov = ((const float4*)ob)[i];
    const float4 xv = ((const float4*)x)[i];
    const float o[4]  = {ov.x, ov.y, ov.z, ov.w};
    const float xo[4] = {xv.x, xv.y, xv.z, xv.w};
    float res[4];
    #pragma unroll
    for (int j = 0; j < 4; ++j) {
        const int c = c0 + j;
        const float mu  = bs[c] * (1.f / (float)NN);
        const float var = bq[c] * (1.f / (float)NN) - mu * mu;
        const float bn  = g[c] * (o[j] - mu) * rsqrtf(var + 1e-5f) + bb[c];
        res[j] = (xo[j] + fmaxf(bn, 0.f)) * 0.5f;
    }
    ((float4*)x)[i] = make_float4(res[0], res[1], res[2], res[3]);
}

// ---- transposed edge update ----
__global__ void __launch_bounds__(256) k_edge_upd_T(float* ea,
        const unsigned short* __restrict__ W1epk, const unsigned short* __restrict__ e2pk,
        const float* __restrict__ e2b, const float* __restrict__ xs1,
        const float* __restrict__ xd1, const int* __restrict__ srcp,
        const int* __restrict__ dstp)
{
    __shared__ unsigned short s_hid[64 * 128];   // bf16, 16B-slot XOR swizzled
    __shared__ float s_b2[128];
    const int t = threadIdx.x, w = t >> 6, l = t & 63;
    const int row0b = blockIdx.x * 64;
    if (t < 128) s_b2[t] = e2b[t];
    const int el = w * 16 + (l & 15);
    const int e = row0b + el;
    const int q = l >> 4, kq = q * 8;
    f32x4 acc1[8] = {};
    #pragma unroll
    for (int kb = 0; kb < 4; ++kb) {
        const bf16x8 bea = load_a8(ea + (size_t)e * HD + kb * 32 + kq, true);
        #pragma unroll
        for (int nt = 0; nt < 8; ++nt) {
            const bf16x8 aW = *(const bf16x8*)(W1epk + (((size_t)(kb * 8 + nt) * 64 + l) << 3));
            acc1[nt] = __builtin_amdgcn_mfma_f32_16x16x32_bf16(aW, bea, acc1[nt], 0, 0, 0);
        }
    }
    {
        const int sn = srcp[e], dn = dstp[e];
        const float* ps = xs1 + (size_t)sn * HD + q * 4;
        const float* pd = xd1 + (size_t)dn * HD + q * 4;
        #pragma unroll
        for (int nt = 0; nt < 8; ++nt) {
            const float4 sv = *(const float4*)(ps + nt * 16);
            const float4 dv = *(const float4*)(pd + nt * 16);
            float4 h;
            h.x = fmaxf(acc1[nt][0] + sv.x + dv.x, 0.f);
            h.y = fmaxf(acc1[nt][1] + sv.y + dv.y, 0.f);
            h.z = fmaxf(acc1[nt][2] + sv.z + dv.z, 0.f);
            h.w = fmaxf(acc1[nt][3] + sv.w + dv.w, 0.f);
            const int bcol = nt * 32 + q * 8;
            const int slot = bcol >> 4;
            const int ba = el * 256 + ((slot ^ (el & 7)) << 4) + (bcol & 15);
            *(bf16x4*)((char*)s_hid + ba) = pack4(h);
        }
    }
    __syncthreads();
    f32x4 acc2[8] = {};
    #pragma unroll
    for (int kb = 0; kb < 4; ++kb) {
        const int slot = kb * 4 + q;
        const int ba = el * 256 + ((slot ^ (el & 7)) << 4);
        const bf16x8 bh = *(const bf16x8*)((const char*)s_hid + ba);
        #pragma unroll
        for (int nt = 0; nt < 8; ++nt) {
            const bf16x8 aW = *(const bf16x8*)(e2pk + (((size_t)(kb * 8 + nt) * 64 + l) << 3));
            acc2[nt] = __builtin_amdgcn_mfma_f32_16x16x32_bf16(aW, bh, acc2[nt], 0, 0, 0);
        }
    }
    {
        float* pe = ea + (size_t)e * HD + q * 4;
        #pragma unroll
        for (int nt = 0; nt < 8; ++nt) {
            const float4 eo = *(const float4*)(pe + nt * 16);
            const float4 bv = *(const float4*)(&s_b2[nt * 16 + q * 4]);
            float4 o;
            o.x = eo.x + (acc2[nt][0] + bv.x) * 0.5f;
            o.y = eo.y + (acc2[nt][1] + bv.y) * 0.5f;
            o.z = eo.z + (acc2[nt][2] + bv.z) * 0.5f;
            o.w = eo.w + (acc2[nt][3] + bv.w) * 0.5f;
            *(float4*)(pe + nt * 16) = o;
        }
    }
}

extern "C" void kernel_launch(void* const* d_in, const int* in_sizes, int n_in,
                              void* d_out, int out_size, void* d_ws, size_t ws_size,
                              hipStream_t stream)
{
    const float* x0    = (const float*)d_in[0];
    const float* eatr  = (const float*)d_in[1];
    const float* teatr = (const float*)d_in[2];
    const float* nodeW = (const float*)d_in[3];
    const float* nodeb = (const float*)d_in[4];
    const float* edgeW = (const float*)d_in[5];
    const float* edgeb = (const float*)d_in[6];
    const float* preW  = (const float*)d_in[7];
    const float* preb  = (const float*)d_in[8];
    const float* postW = (const float*)d_in[9];
    const float* postb = (const float*)d_in[10];
    const float* linW  = (const float*)d_in[11];
    const float* linb  = (const float*)d_in[12];
    const float* bng   = (const float*)d_in[13];
    const float* bnb   = (const float*)d_in[14];
    const float* em1W  = (const float*)d_in[15];
    const float* em1b  = (const float*)d_in[16];
    const float* em2W  = (const float*)d_in[17];
    const float* em2b  = (const float*)d_in[18];
    const int*   eidx  = (const int*)d_in[19];
    const int* srcp = eidx;
    const int* dstp = eidx + NE;

    float* out_x  = (float*)d_out;
    float* out_ea = out_x + (size_t)NN * HD;
    float* out_te = out_ea + (size_t)NE * HD;

    const size_t NH = (size_t)NN * HD;
    const size_t EH = (size_t)NE * HD;
    float* xd   = (float*)d_ws;
    float* xs   = xd + NH;
    float* outb = xs + NH;
    float* stats = outb + NH;          // [0]=sum log; [128..255]=bn sum; [256..383]=bn sumsq
    int*   cnt      = (int*)(stats + 512);
    int*   row_start = cnt + NN;       // NN+1
    int*   cursor   = row_start + NN + 1;
    int*   tmpincl  = cursor + NN;
    int*   part     = tmpincl + NN;    // 256
    int*   poff     = part + 256;      // 256
    int*   sppos    = poff + 256;      // NE
    unsigned short* mbuf = (unsigned short*)(((uintptr_t)(sppos + NE) + 15) & ~(uintptr_t)15);
    unsigned short* aggb = mbuf + EH;                  // [NN][1536] bf16: agg | agg*amp | agg*att
    unsigned short* pk   = aggb + (size_t)NN * 1536;
    const size_t KBSZ = 512 * 8;   // ushorts per kb
    unsigned short* pkPost = pk;                       // 104 kbs
    unsigned short* pkPre  = pkPost + 104 * KBSZ;      // 24 kbs
    unsigned short* pkEm1  = pkPre  + 24 * KBSZ;       // 24 kbs
    unsigned short* pkLin  = pkEm1  + 24 * KBSZ;       // 8 kbs
    unsigned short* pkEm2  = pkLin  + 8 * KBSZ;        // 8 kbs
    unsigned short* pkNode = pkEm2  + 8 * KBSZ;        // 2 kbs
    unsigned short* pkEdge = pkNode + 2 * KBSZ;        // 1 kb

    hipMemsetAsync(cnt, 0, NN * sizeof(int), stream);
    hipMemsetAsync(stats, 0, 512 * sizeof(float), stream);

    // pack all weights
    k_packW<<<208, 256, 0, stream>>>(postW, pkPost, 3328);
    k_packW<<<48, 256, 0, stream>>>(preW,  pkPre,  768);
    k_packW<<<48, 256, 0, stream>>>(em1W,  pkEm1,  768);
    k_packW<<<16, 256, 0, stream>>>(linW,  pkLin,  256);
    k_packW<<<16, 256, 0, stream>>>(em2W,  pkEm2,  256);
    k_packW<<<4, 256, 0, stream>>>(nodeW, pkNode, 64);
    k_packW<<<2, 256, 0, stream>>>(edgeW, pkEdge, 32);

    // prologue embeddings (transposed)
    k_gemm_T<1><<<(NE + 63) / 64, 256, 0, stream>>>(eatr, pkEdge, edgeb, out_ea, NE);
    k_gemm_T<1><<<(NTE + 63) / 64, 256, 0, stream>>>(teatr, pkEdge, edgeb, out_te, NTE);
    k_gemm_T<2><<<(NN + 63) / 64, 256, 0, stream>>>(x0, pkNode, nodeb, out_x, NN);

    // CSR build
    k_count<<<(NE + 255) / 256, 256, 0, stream>>>(dstp, cnt, NE);
    k_avglog<<<256, 256, 0, stream>>>(cnt, stats);
    k_scan_block<<<SCAN_B, 256, 0, stream>>>(cnt, tmpincl, part);
    k_scan_part<<<1, 256, 0, stream>>>(part, poff, SCAN_B);
    k_scan_add<<<SCAN_B, 256, 0, stream>>>(tmpincl, cnt, poff, row_start, cursor);
    k_scatter<<<(NE + 255) / 256, 256, 0, stream>>>(dstp, cursor, sppos);

    const int gn = (NN + 63) / 64;
    const int ge = NE / 64;

    for (int l = 0; l < NL; ++l) {
        const unsigned short* Wd_pk  = pkPre + (size_t)(l * 12 + 0) * KBSZ;
        const unsigned short* Ws_pk  = pkPre + (size_t)(l * 12 + 4) * KBSZ;
        const unsigned short* We_pk  = pkPre + (size_t)(l * 12 + 8) * KBSZ;
        const unsigned short* W1s_pk = pkEm1 + (size_t)(l * 12 + 0) * KBSZ;
        const unsigned short* W1d_pk = pkEm1 + (size_t)(l * 12 + 4) * KBSZ;
        const unsigned short* W1e_pk = pkEm1 + (size_t)(l * 12 + 8) * KBSZ;
        const unsigned short* PW_pk  = pkPost + (size_t)l * 52 * KBSZ;
        const unsigned short* lin_pk = pkLin + (size_t)l * 4 * KBSZ;
        const unsigned short* em2_pk = pkEm2 + (size_t)l * 4 * KBSZ;
        const float* pbl = preb + l * HD;
        const float* pob = postb + l * HD;
        const float* lb  = linb + l * HD;
        const float* g_  = bng + l * HD;
        const float* b_  = bnb + l * HD;
        const float* e1b = em1b + l * HD;
        const float* e2b = em2b + l * HD;

        hipMemsetAsync(stats + 128, 0, 256 * sizeof(float), stream);

        k_gemm2_T<4><<<gn, 256, 0, stream>>>(out_x, Wd_pk, Ws_pk, pbl, xd, xs, NN);
        k_msg_T<<<ge, 256, 0, stream>>>(out_ea, We_pk, xs, srcp, sppos, mbuf);
        k_agg<<<(NN + 3) / 4, 256, 0, stream>>>(mbuf, row_start, xd, stats, aggb);
        k_post_lin_T<<<gn, 256, 0, stream>>>(out_x, aggb, PW_pk, pob, lin_pk, lb, outb, NN);
        k_bnstats<<<256, 256, 0, stream>>>(outb, stats + 128, stats + 256, NN);
        k_xupdate<<<NN * 32 / 256, 256, 0, stream>>>(out_x, outb, stats + 128, stats + 256, g_, b_);
        k_gemm2_T<4><<<gn, 256, 0, stream>>>(out_x, W1d_pk, W1s_pk, e1b, xd, xs, NN);
        k_edge_upd_T<<<ge, 256, 0, stream>>>(out_ea, W1e_pk, em2_pk, e2b, xs, xd, srcp, dstp);
    }
}

// Round 8
// 1403.948 us; speedup vs baseline: 1.1833x; 1.0353x over previous
//
#include <hip/hip_runtime.h>
#include <math.h>

#define NN  50000
#define NE  400000
#define NTE 50000
#define FIN 64
#define EDIM 32
#define HD  128
#define NL  2
#define SCAN_B ((NN + 255) / 256)

typedef __attribute__((ext_vector_type(8))) short bf16x8;
typedef __attribute__((ext_vector_type(4))) short bf16x4;
typedef __attribute__((ext_vector_type(4))) float f32x4;

static __device__ __forceinline__ unsigned short f2bf(float f) {
    unsigned u = __float_as_uint(f);
    unsigned r = (u + 0x7fffu + ((u >> 16) & 1u)) >> 16;
    return (unsigned short)r;
}
static __device__ __forceinline__ float bfhi2f(unsigned u) { return __uint_as_float(u & 0xffff0000u); }
static __device__ __forceinline__ float bflo2f(unsigned u) { return __uint_as_float(u << 16); }

static __device__ __forceinline__ bf16x8 load_a8(const float* p, bool ok) {
    bf16x8 a = {};
    if (ok) {
        const float4 v0 = *(const float4*)(p);
        const float4 v1 = *(const float4*)(p + 4);
        a[0] = (short)f2bf(v0.x); a[1] = (short)f2bf(v0.y);
        a[2] = (short)f2bf(v0.z); a[3] = (short)f2bf(v0.w);
        a[4] = (short)f2bf(v1.x); a[5] = (short)f2bf(v1.y);
        a[6] = (short)f2bf(v1.z); a[7] = (short)f2bf(v1.w);
    }
    return a;
}
static __device__ __forceinline__ bf16x4 pack4(float4 a) {
    bf16x4 v;
    v[0]=(short)f2bf(a.x); v[1]=(short)f2bf(a.y); v[2]=(short)f2bf(a.z); v[3]=(short)f2bf(a.w);
    return v;
}

// ---- pack fp32 W[K][128] into bf16 MFMA frag order: [(kb*8+nt)*64+lane][8] k-contig ----
__global__ void __launch_bounds__(256) k_packW(const float* __restrict__ W,
        unsigned short* __restrict__ out, int K)
{
    const int tid = blockIdx.x * 256 + threadIdx.x;
    const int total = (K / 32) * 512;
    if (tid >= total) return;
    const int lane = tid & 63, nt = (tid >> 6) & 7, kb = tid >> 9;
    const int k0 = kb * 32 + (lane >> 4) * 8;
    const int col = nt * 16 + (lane & 15);
    bf16x8 v;
    #pragma unroll
    for (int j = 0; j < 8; ++j)
        v[j] = (short)f2bf(W[(size_t)(k0 + j) * HD + col]);
    *(bf16x8*)(out + (size_t)tid * 8) = v;
}

// ---- fold layer-0 message weight: Wf = edgeW@We0 [32][128], bf = edgeb@We0 [128] ----
__global__ void __launch_bounds__(256) k_foldW(const float* __restrict__ edgeW,
        const float* __restrict__ edgeb, const float* __restrict__ We0,
        float* __restrict__ Wf, float* __restrict__ bf)
{
    const int tid = blockIdx.x * 256 + threadIdx.x;
    if (tid < 4096) {
        const int k = tid >> 7, c = tid & 127;
        float s = 0.f;
        for (int j = 0; j < 128; ++j) s += edgeW[k * HD + j] * We0[(size_t)j * HD + c];
        Wf[tid] = s;
    } else if (tid < 4224) {
        const int c = tid - 4096;
        float s = 0.f;
        for (int j = 0; j < 128; ++j) s += edgeb[j] * We0[(size_t)j * HD + c];
        bf[c] = s;
    }
}

// ---- transposed MFMA GEMM: C = A@W (+bias); lane owns one row, float4 stores ----
template<int KB>
__global__ void __launch_bounds__(256) k_gemm_T(const float* A,
        const unsigned short* __restrict__ Wpk, const float* __restrict__ bias,
        float* C, int M)
{
    const int t = threadIdx.x, w = t >> 6, l = t & 63;
    const int n = blockIdx.x * 64 + w * 16 + (l & 15);
    const bool ok = n < M;
    const int q = l >> 4;
    const int K = KB * 32;
    f32x4 acc[8] = {};
    #pragma unroll
    for (int kb = 0; kb < KB; ++kb) {
        const bf16x8 b = load_a8(A + (size_t)n * K + kb * 32 + q * 8, ok);
        #pragma unroll
        for (int nt = 0; nt < 8; ++nt) {
            const bf16x8 aW = *(const bf16x8*)(Wpk + (((size_t)(kb * 8 + nt) * 64 + l) << 3));
            acc[nt] = __builtin_amdgcn_mfma_f32_16x16x32_bf16(aW, b, acc[nt], 0, 0, 0);
        }
    }
    if (ok) {
        float* pc = C + (size_t)n * HD + q * 4;
        #pragma unroll
        for (int nt = 0; nt < 8; ++nt) {
            const int col = nt * 16 + q * 4;
            float4 bv = bias ? *(const float4*)(bias + col) : make_float4(0.f,0.f,0.f,0.f);
            float4 o;
            o.x = acc[nt][0] + bv.x; o.y = acc[nt][1] + bv.y;
            o.z = acc[nt][2] + bv.z; o.w = acc[nt][3] + bv.w;
            *(float4*)(pc + nt * 16) = o;
        }
    }
}

// ---- transposed dual GEMM, bf16 outputs: C0 = bf16(A@W0 + b0), C1 = bf16(A@W1) ----
template<int KB>
__global__ void __launch_bounds__(256) k_gemm2_Tb(const float* A,
        const unsigned short* __restrict__ W0, const unsigned short* __restrict__ W1,
        const float* __restrict__ b0, unsigned short* C0, unsigned short* C1, int M)
{
    const int t = threadIdx.x, w = t >> 6, l = t & 63;
    const int n = blockIdx.x * 64 + w * 16 + (l & 15);
    const bool ok = n < M;
    const int q = l >> 4;
    const int K = KB * 32;
    f32x4 a0[8] = {}, a1[8] = {};
    #pragma unroll
    for (int kb = 0; kb < KB; ++kb) {
        const bf16x8 b = load_a8(A + (size_t)n * K + kb * 32 + q * 8, ok);
        #pragma unroll
        for (int nt = 0; nt < 8; ++nt) {
            const bf16x8 u = *(const bf16x8*)(W0 + (((size_t)(kb * 8 + nt) * 64 + l) << 3));
            const bf16x8 v = *(const bf16x8*)(W1 + (((size_t)(kb * 8 + nt) * 64 + l) << 3));
            a0[nt] = __builtin_amdgcn_mfma_f32_16x16x32_bf16(u, b, a0[nt], 0, 0, 0);
            a1[nt] = __builtin_amdgcn_mfma_f32_16x16x32_bf16(v, b, a1[nt], 0, 0, 0);
        }
    }
    if (ok) {
        unsigned short* p0 = C0 + (size_t)n * HD + q * 4;
        unsigned short* p1 = C1 + (size_t)n * HD + q * 4;
        #pragma unroll
        for (int nt = 0; nt < 8; ++nt) {
            const int col = nt * 16 + q * 4;
            float4 bv = b0 ? *(const float4*)(b0 + col) : make_float4(0.f,0.f,0.f,0.f);
            float4 o0, o1;
            o0.x = a0[nt][0] + bv.x; o0.y = a0[nt][1] + bv.y;
            o0.z = a0[nt][2] + bv.z; o0.w = a0[nt][3] + bv.w;
            o1.x = a1[nt][0]; o1.y = a1[nt][1]; o1.z = a1[nt][2]; o1.w = a1[nt][3];
            *(bf16x4*)(p0 + nt * 16) = pack4(o0);
            *(bf16x4*)(p1 + nt * 16) = pack4(o1);
        }
    }
}

// ---- degree count ----
__global__ void __launch_bounds__(256) k_count(const int* __restrict__ d, int* __restrict__ cnt, int E)
{
    const int e = blockIdx.x * 256 + threadIdx.x;
    if (e < E) atomicAdd(&cnt[d[e]], 1);
}

// ---- mean(log(cnt+1)) numerator ----
__global__ void __launch_bounds__(256) k_avglog(const int* __restrict__ cnt, float* __restrict__ stats)
{
    float s = 0.f;
    for (int n = blockIdx.x * 256 + threadIdx.x; n < NN; n += gridDim.x * 256)
        s += logf((float)cnt[n] + 1.f);
    #pragma unroll
    for (int off = 32; off > 0; off >>= 1) s += __shfl_down(s, off);
    __shared__ float ls[4];
    if ((threadIdx.x & 63) == 0) ls[threadIdx.x >> 6] = s;
    __syncthreads();
    if (threadIdx.x == 0) unsafeAtomicAdd(stats, ls[0] + ls[1] + ls[2] + ls[3]);
}

// ---- CSR build ----
__global__ void __launch_bounds__(256) k_scan_block(const int* __restrict__ cnt,
        int* __restrict__ incl, int* __restrict__ part)
{
    __shared__ int s[256];
    const int t = threadIdx.x;
    const int i = blockIdx.x * 256 + t;
    const int v = (i < NN) ? cnt[i] : 0;
    s[t] = v;
    __syncthreads();
    #pragma unroll
    for (int off = 1; off < 256; off <<= 1) {
        const int x = (t >= off) ? s[t - off] : 0;
        __syncthreads();
        s[t] += x;
        __syncthreads();
    }
    if (i < NN) incl[i] = s[t];
    if (t == 255) part[blockIdx.x] = s[255];
}

__global__ void __launch_bounds__(256) k_scan_part(const int* __restrict__ part,
        int* __restrict__ poff, int np)
{
    __shared__ int s[256];
    const int t = threadIdx.x;
    const int v = (t < np) ? part[t] : 0;
    s[t] = v;
    __syncthreads();
    #pragma unroll
    for (int off = 1; off < 256; off <<= 1) {
        const int x = (t >= off) ? s[t - off] : 0;
        __syncthreads();
        s[t] += x;
        __syncthreads();
    }
    poff[t] = s[t] - v;
}

__global__ void __launch_bounds__(256) k_scan_add(const int* __restrict__ incl,
        const int* __restrict__ cnt, const int* __restrict__ poff,
        int* __restrict__ row_start, int* __restrict__ cursor)
{
    const int i = blockIdx.x * 256 + threadIdx.x;
    if (i < NN) {
        const int excl = incl[i] - cnt[i] + poff[blockIdx.x];
        row_start[i] = excl;
        cursor[i] = excl;
    }
    if (i == 0) row_start[NN] = NE;
}

__global__ void __launch_bounds__(256) k_scatter(const int* __restrict__ dstp,
        int* cursor, int* __restrict__ sppos)
{
    const int e = blockIdx.x * 256 + threadIdx.x;
    if (e < NE) sppos[e] = atomicAdd(&cursor[dstp[e]], 1);
}

// ---- transposed msg: m' = EA@W (+bias) + xs[src]; bf16 row-scatter to mbuf[sppos] ----
// KB=1: EA=eatr (layer-0 folded weights); KB=4: EA=ea. xs table is bf16.
template<int KB>
__global__ void __launch_bounds__(256) k_msg_T(const float* __restrict__ EA,
        const unsigned short* __restrict__ Wpk, const float* __restrict__ bias,
        const unsigned short* __restrict__ xsb, const int* __restrict__ srcp,
        const int* __restrict__ sppos, unsigned short* __restrict__ mbuf)
{
    const int t = threadIdx.x, w = t >> 6, l = t & 63;
    const int e = blockIdx.x * 64 + w * 16 + (l & 15);
    const int q = l >> 4;
    f32x4 acc[8] = {};
    #pragma unroll
    for (int kb = 0; kb < KB; ++kb) {
        const bf16x8 bea = load_a8(EA + (size_t)e * (KB * 32) + kb * 32 + q * 8, true);
        #pragma unroll
        for (int nt = 0; nt < 8; ++nt) {
            const bf16x8 aW = *(const bf16x8*)(Wpk + (((size_t)(kb * 8 + nt) * 64 + l) << 3));
            acc[nt] = __builtin_amdgcn_mfma_f32_16x16x32_bf16(aW, bea, acc[nt], 0, 0, 0);
        }
    }
    const int sn = srcp[e], sp = sppos[e];
    const unsigned short* ps = xsb + (size_t)sn * HD + q * 4;
    unsigned short* pm = mbuf + (size_t)sp * HD + q * 4;
    #pragma unroll
    for (int nt = 0; nt < 8; ++nt) {
        const uint2 su = *(const uint2*)(ps + nt * 16);
        float4 o;
        o.x = acc[nt][0] + bflo2f(su.x); o.y = acc[nt][1] + bfhi2f(su.x);
        o.z = acc[nt][2] + bflo2f(su.y); o.w = acc[nt][3] + bfhi2f(su.y);
        if (bias) {
            const float4 bv = *(const float4*)(bias + nt * 16 + q * 4);
            o.x += bv.x; o.y += bv.y; o.z += bv.z; o.w += bv.w;
        }
        *(bf16x4*)(pm + nt * 16) = pack4(o);
    }
}

// ---- CSR aggregation; shift by xd[n] (bf16); writes [agg | agg*amp | agg*att] bf16 [NN][1536] ----
__global__ void __launch_bounds__(256) k_agg(const unsigned short* __restrict__ mbuf,
        const int* __restrict__ rs, const unsigned short* __restrict__ xdb,
        const float* __restrict__ stats, unsigned short* __restrict__ aggb)
{
    const int n = blockIdx.x * 4 + (threadIdx.x >> 6);
    if (n >= NN) return;
    const int lane = threadIdx.x & 63;
    const int c = lane * 2;
    const int s = rs[n], e = rs[n + 1];
    const unsigned xu = *(const unsigned*)(xdb + (size_t)n * HD + c);
    const float xv0 = bflo2f(xu), xv1 = bfhi2f(xu);
    float s0=0.f, s1=0.f, q0=0.f, q1=0.f;
    float mn0=INFINITY, mn1=INFINITY, mx0=-INFINITY, mx1=-INFINITY;
    for (int i = s; i < e; ++i) {
        const unsigned u = *(const unsigned*)(mbuf + (size_t)i * HD + c);
        const float v0 = bflo2f(u), v1 = bfhi2f(u);
        s0 += v0; s1 += v1;
        q0 += v0 * v0; q1 += v1 * v1;
        mn0 = fminf(mn0, v0); mn1 = fminf(mn1, v1);
        mx0 = fmaxf(mx0, v0); mx1 = fmaxf(mx1, v1);
    }
    const int deg = e - s;
    const float inv = 1.f / (float)(deg > 1 ? deg : 1);
    const float fd = (float)deg * inv;          // 0 if deg==0 else 1
    const float m0p = s0 * inv, m1p = s1 * inv;
    const float sd0 = sqrtf(fmaxf(q0 * inv - m0p * m0p, 0.f) + 1e-5f);
    const float sd1 = sqrtf(fmaxf(q1 * inv - m1p * m1p, 0.f) + 1e-5f);
    const bool has = deg > 0;
    const float v0[4] = { m0p + fd * xv0, has ? mn0 + xv0 : 0.f,
                          has ? mx0 + xv0 : 0.f, sd0 };
    const float v1[4] = { m1p + fd * xv1, has ? mn1 + xv1 : 0.f,
                          has ? mx1 + xv1 : 0.f, sd1 };
    const float avg = stats[0] * (1.f / (float)NN);
    const float lg = logf(fmaxf((float)deg, 1.f) + 1.f);
    const float amp = lg / avg, att = avg / lg;
    unsigned* a = (unsigned*)(aggb + (size_t)n * 1536 + c);
    #pragma unroll
    for (int sct = 0; sct < 4; ++sct) {
        a[sct * 64]       = (unsigned)f2bf(v0[sct])       | ((unsigned)f2bf(v1[sct]) << 16);
        a[256 + sct * 64] = (unsigned)f2bf(v0[sct] * amp) | ((unsigned)f2bf(v1[sct] * amp) << 16);
        a[512 + sct * 64] = (unsigned)f2bf(v0[sct] * att) | ((unsigned)f2bf(v1[sct] * att) << 16);
    }
}

// ---- transposed post+lin: out = [x|agg3]@PW + pb (ONE acc set); outb = out@linW + lb ----
__global__ void __launch_bounds__(256) k_post_lin_T(const float* __restrict__ x,
        const unsigned short* __restrict__ aggb, const unsigned short* __restrict__ PWpk,
        const float* __restrict__ pb, const unsigned short* __restrict__ LNpk,
        const float* __restrict__ lb, float* __restrict__ outb, int M)
{
    __shared__ unsigned short s_o16[64 * 128];   // swizzled bf16 out tile
    const int t = threadIdx.x, w = t >> 6, l = t & 63;
    const int el = w * 16 + (l & 15);
    const int n = blockIdx.x * 64 + el;
    const bool ok = n < M;
    const int q = l >> 4;
    f32x4 acc[8] = {};
    #pragma unroll
    for (int kb = 0; kb < 4; ++kb) {
        const bf16x8 b = load_a8(x + (size_t)n * HD + kb * 32 + q * 8, ok);
        #pragma unroll
        for (int nt = 0; nt < 8; ++nt) {
            const bf16x8 aW = *(const bf16x8*)(PWpk + (((size_t)(kb * 8 + nt) * 64 + l) << 3));
            acc[nt] = __builtin_amdgcn_mfma_f32_16x16x32_bf16(aW, b, acc[nt], 0, 0, 0);
        }
    }
    const unsigned short* arow = aggb + (size_t)n * 1536 + q * 8;
    #pragma unroll 4
    for (int kb = 4; kb < 52; ++kb) {
        bf16x8 b = {};
        if (ok) b = *(const bf16x8*)(arow + (size_t)(kb - 4) * 32);
        #pragma unroll
        for (int nt = 0; nt < 8; ++nt) {
            const bf16x8 aW = *(const bf16x8*)(PWpk + (((size_t)(kb * 8 + nt) * 64 + l) << 3));
            acc[nt] = __builtin_amdgcn_mfma_f32_16x16x32_bf16(aW, b, acc[nt], 0, 0, 0);
        }
    }
    #pragma unroll
    for (int nt = 0; nt < 8; ++nt) {
        const int col = nt * 16 + q * 4;
        const float4 bv = *(const float4*)(pb + col);
        float4 o;
        o.x = acc[nt][0] + bv.x; o.y = acc[nt][1] + bv.y;
        o.z = acc[nt][2] + bv.z; o.w = acc[nt][3] + bv.w;
        const int bcol = nt * 32 + q * 8;
        const int slot = bcol >> 4;
        const int ba = el * 256 + ((slot ^ (el & 7)) << 4) + (bcol & 15);
        *(bf16x4*)((char*)s_o16 + ba) = pack4(o);
    }
    __syncthreads();
    f32x4 acc2[8] = {};
    #pragma unroll
    for (int kb = 0; kb < 4; ++kb) {
        const int slot = kb * 4 + q;
        const int ba = el * 256 + ((slot ^ (el & 7)) << 4);
        const bf16x8 bh = *(const bf16x8*)((const char*)s_o16 + ba);
        #pragma unroll
        for (int nt = 0; nt < 8; ++nt) {
            const bf16x8 aW = *(const bf16x8*)(LNpk + (((size_t)(kb * 8 + nt) * 64 + l) << 3));
            acc2[nt] = __builtin_amdgcn_mfma_f32_16x16x32_bf16(aW, bh, acc2[nt], 0, 0, 0);
        }
    }
    if (ok) {
        float* pc = outb + (size_t)n * HD + q * 4;
        #pragma unroll
        for (int nt = 0; nt < 8; ++nt) {
            const int col = nt * 16 + q * 4;
            const float4 bv = *(const float4*)(lb + col);
            float4 o;
            o.x = acc2[nt][0] + bv.x; o.y = acc2[nt][1] + bv.y;
            o.z = acc2[nt][2] + bv.z; o.w = acc2[nt][3] + bv.w;
            *(float4*)(pc + nt * 16) = o;
        }
    }
}

// ---- BN column sums ----
__global__ void __launch_bounds__(256) k_bnstats(const float* __restrict__ ob,
        float* __restrict__ bs, float* __restrict__ bq, int M)
{
    const int c = threadIdx.x & 127;
    const int gsub = threadIdx.x >> 7;
    float s = 0.f, qq = 0.f;
    for (int rr = blockIdx.x * 2 + gsub; rr < M; rr += gridDim.x * 2) {
        const float v = ob[(size_t)rr * HD + c];
        s += v; qq += v * v;
    }
    __shared__ float ls[2][HD], lq[2][HD];
    ls[gsub][c] = s; lq[gsub][c] = qq;
    __syncthreads();
    if (gsub == 0) {
        unsafeAtomicAdd(&bs[c], ls[0][c] + ls[1][c]);
        unsafeAtomicAdd(&bq[c], lq[0][c] + lq[1][c]);
    }
}

// ---- x = (x + relu(bn(out)))/2 ----
__global__ void __launch_bounds__(256) k_xupdate(float* x, const float* __restrict__ ob,
        const float* __restrict__ bs, const float* __restrict__ bq,
        const float* __restrict__ g, const float* __restrict__ bb)
{
    const int i = blockIdx.x * 256 + threadIdx.x;
    const int c0 = (i & 31) * 4;
    const float4 ov = ((const float4*)ob)[i];
    const float4 xv = ((const float4*)x)[i];
    const float o[4]  = {ov.x, ov.y, ov.z, ov.w};
    const float xo[4] = {xv.x, xv.y, xv.z, xv.w};
    float res[4];
    #pragma unroll
    for (int j = 0; j < 4; ++j) {
        const int c = c0 + j;
        const float mu  = bs[c] * (1.f / (float)NN);
        const float var = bq[c] * (1.f / (float)NN) - mu * mu;
        const float bn  = g[c] * (o[j] - mu) * rsqrtf(var + 1e-5f) + bb[c];
        res[j] = (xo[j] + fmaxf(bn, 0.f)) * 0.5f;
    }
    ((float4*)x)[i] = make_float4(res[0], res[1], res[2], res[3]);
}

// ---- transposed edge update (bf16 gather tables) ----
__global__ void __launch_bounds__(256) k_edge_upd_T(float* ea,
        const unsigned short* __restrict__ W1epk, const unsigned short* __restrict__ e2pk,
        const float* __restrict__ e2b, const unsigned short* __restrict__ xs1b,
        const unsigned short* __restrict__ xd1b, const int* __restrict__ srcp,
        const int* __restrict__ dstp)
{
    __shared__ unsigned short s_hid[64 * 128];   // bf16, 16B-slot XOR swizzled
    __shared__ float s_b2[128];
    const int t = threadIdx.x, w = t >> 6, l = t & 63;
    const int row0b = blockIdx.x * 64;
    if (t < 128) s_b2[t] = e2b[t];
    const int el = w * 16 + (l & 15);
    const int e = row0b + el;
    const int q = l >> 4, kq = q * 8;
    f32x4 acc1[8] = {};
    #pragma unroll
    for (int kb = 0; kb < 4; ++kb) {
        const bf16x8 bea = load_a8(ea + (size_t)e * HD + kb * 32 + kq, true);
        #pragma unroll
        for (int nt = 0; nt < 8; ++nt) {
            const bf16x8 aW = *(const bf16x8*)(W1epk + (((size_t)(kb * 8 + nt) * 64 + l) << 3));
            acc1[nt] = __builtin_amdgcn_mfma_f32_16x16x32_bf16(aW, bea, acc1[nt], 0, 0, 0);
        }
    }
    {
        const int sn = srcp[e], dn = dstp[e];
        const unsigned short* ps = xs1b + (size_t)sn * HD + q * 4;
        const unsigned short* pd = xd1b + (size_t)dn * HD + q * 4;
        #pragma unroll
        for (int nt = 0; nt < 8; ++nt) {
            const uint2 su = *(const uint2*)(ps + nt * 16);
            const uint2 du = *(const uint2*)(pd + nt * 16);
            float4 h;
            h.x = fmaxf(acc1[nt][0] + bflo2f(su.x) + bflo2f(du.x), 0.f);
            h.y = fmaxf(acc1[nt][1] + bfhi2f(su.x) + bfhi2f(du.x), 0.f);
            h.z = fmaxf(acc1[nt][2] + bflo2f(su.y) + bflo2f(du.y), 0.f);
            h.w = fmaxf(acc1[nt][3] + bfhi2f(su.y) + bfhi2f(du.y), 0.f);
            const int bcol = nt * 32 + q * 8;
            const int slot = bcol >> 4;
            const int ba = el * 256 + ((slot ^ (el & 7)) << 4) + (bcol & 15);
            *(bf16x4*)((char*)s_hid + ba) = pack4(h);
        }
    }
    __syncthreads();
    f32x4 acc2[8] = {};
    #pragma unroll
    for (int kb = 0; kb < 4; ++kb) {
        const int slot = kb * 4 + q;
        const int ba = el * 256 + ((slot ^ (el & 7)) << 4);
        const bf16x8 bh = *(const bf16x8*)((const char*)s_hid + ba);
        #pragma unroll
        for (int nt = 0; nt < 8; ++nt) {
            const bf16x8 aW = *(const bf16x8*)(e2pk + (((size_t)(kb * 8 + nt) * 64 + l) << 3));
            acc2[nt] = __builtin_amdgcn_mfma_f32_16x16x32_bf16(aW, bh, acc2[nt], 0, 0, 0);
        }
    }
    {
        float* pe = ea + (size_t)e * HD + q * 4;
        #pragma unroll
        for (int nt = 0; nt < 8; ++nt) {
            const float4 eo = *(const float4*)(pe + nt * 16);
            const float4 bv = *(const float4*)(&s_b2[nt * 16 + q * 4]);
            float4 o;
            o.x = eo.x + (acc2[nt][0] + bv.x) * 0.5f;
            o.y = eo.y + (acc2[nt][1] + bv.y) * 0.5f;
            o.z = eo.z + (acc2[nt][2] + bv.z) * 0.5f;
            o.w = eo.w + (acc2[nt][3] + bv.w) * 0.5f;
            *(float4*)(pe + nt * 16) = o;
        }
    }
}

extern "C" void kernel_launch(void* const* d_in, const int* in_sizes, int n_in,
                              void* d_out, int out_size, void* d_ws, size_t ws_size,
                              hipStream_t stream)
{
    const float* x0    = (const float*)d_in[0];
    const float* eatr  = (const float*)d_in[1];
    const float* teatr = (const float*)d_in[2];
    const float* nodeW = (const float*)d_in[3];
    const float* nodeb = (const float*)d_in[4];
    const float* edgeW = (const float*)d_in[5];
    const float* edgeb = (const float*)d_in[6];
    const float* preW  = (const float*)d_in[7];
    const float* preb  = (const float*)d_in[8];
    const float* postW = (const float*)d_in[9];
    const float* postb = (const float*)d_in[10];
    const float* linW  = (const float*)d_in[11];
    const float* linb  = (const float*)d_in[12];
    const float* bng   = (const float*)d_in[13];
    const float* bnb   = (const float*)d_in[14];
    const float* em1W  = (const float*)d_in[15];
    const float* em1b  = (const float*)d_in[16];
    const float* em2W  = (const float*)d_in[17];
    const float* em2b  = (const float*)d_in[18];
    const int*   eidx  = (const int*)d_in[19];
    const int* srcp = eidx;
    const int* dstp = eidx + NE;

    float* out_x  = (float*)d_out;
    float* out_ea = out_x + (size_t)NN * HD;
    float* out_te = out_ea + (size_t)NE * HD;

    const size_t NH = (size_t)NN * HD;
    const size_t EH = (size_t)NE * HD;
    unsigned short* xdb = (unsigned short*)d_ws;     // [NN][128] bf16
    unsigned short* xsb = xdb + NH;                  // [NN][128] bf16
    float* outb  = (float*)(xsb + NH);
    float* stats = outb + NH;          // [0]=sum log; [128..255]=bn sum; [256..383]=bn sumsq
    float* Wf    = stats + 512;        // folded layer-0 msg weight [32][128]
    float* bfold = Wf + 4096;          // folded bias [128]
    int*   cnt      = (int*)(bfold + 128);
    int*   row_start = cnt + NN;       // NN+1
    int*   cursor   = row_start + NN + 1;
    int*   tmpincl  = cursor + NN;
    int*   part     = tmpincl + NN;    // 256
    int*   poff     = part + 256;      // 256
    int*   sppos    = poff + 256;      // NE
    unsigned short* mbuf = (unsigned short*)(((uintptr_t)(sppos + NE) + 15) & ~(uintptr_t)15);
    unsigned short* aggb = mbuf + EH;                  // [NN][1536] bf16
    unsigned short* pk   = aggb + (size_t)NN * 1536;
    const size_t KBSZ = 512 * 8;
    unsigned short* pkPost = pk;                       // 104 kbs
    unsigned short* pkPre  = pkPost + 104 * KBSZ;      // 24 kbs
    unsigned short* pkEm1  = pkPre  + 24 * KBSZ;       // 24 kbs
    unsigned short* pkLin  = pkEm1  + 24 * KBSZ;       // 8 kbs
    unsigned short* pkEm2  = pkLin  + 8 * KBSZ;        // 8 kbs
    unsigned short* pkNode = pkEm2  + 8 * KBSZ;        // 2 kbs
    unsigned short* pkEdge = pkNode + 2 * KBSZ;        // 1 kb
    unsigned short* pkWe0f = pkEdge + 1 * KBSZ;        // 1 kb (folded layer-0 msg W)

    hipMemsetAsync(cnt, 0, NN * sizeof(int), stream);
    hipMemsetAsync(stats, 0, 512 * sizeof(float), stream);

    // pack all weights + fold layer-0 msg weight
    k_packW<<<208, 256, 0, stream>>>(postW, pkPost, 3328);
    k_packW<<<48, 256, 0, stream>>>(preW,  pkPre,  768);
    k_packW<<<48, 256, 0, stream>>>(em1W,  pkEm1,  768);
    k_packW<<<16, 256, 0, stream>>>(linW,  pkLin,  256);
    k_packW<<<16, 256, 0, stream>>>(em2W,  pkEm2,  256);
    k_packW<<<4, 256, 0, stream>>>(nodeW, pkNode, 64);
    k_packW<<<2, 256, 0, stream>>>(edgeW, pkEdge, 32);
    k_foldW<<<17, 256, 0, stream>>>(edgeW, edgeb, preW + 256 * HD, Wf, bfold);
    k_packW<<<2, 256, 0, stream>>>(Wf, pkWe0f, 32);

    // prologue embeddings (transposed)
    k_gemm_T<1><<<(NE + 63) / 64, 256, 0, stream>>>(eatr, pkEdge, edgeb, out_ea, NE);
    k_gemm_T<1><<<(NTE + 63) / 64, 256, 0, stream>>>(teatr, pkEdge, edgeb, out_te, NTE);
    k_gemm_T<2><<<(NN + 63) / 64, 256, 0, stream>>>(x0, pkNode, nodeb, out_x, NN);

    // CSR build
    k_count<<<(NE + 255) / 256, 256, 0, stream>>>(dstp, cnt, NE);
    k_avglog<<<256, 256, 0, stream>>>(cnt, stats);
    k_scan_block<<<SCAN_B, 256, 0, stream>>>(cnt, tmpincl, part);
    k_scan_part<<<1, 256, 0, stream>>>(part, poff, SCAN_B);
    k_scan_add<<<SCAN_B, 256, 0, stream>>>(tmpincl, cnt, poff, row_start, cursor);
    k_scatter<<<(NE + 255) / 256, 256, 0, stream>>>(dstp, cursor, sppos);

    const int gn = (NN + 63) / 64;
    const int ge = NE / 64;

    for (int l = 0; l < NL; ++l) {
        const unsigned short* Wd_pk  = pkPre + (size_t)(l * 12 + 0) * KBSZ;
        const unsigned short* Ws_pk  = pkPre + (size_t)(l * 12 + 4) * KBSZ;
        const unsigned short* We_pk  = pkPre + (size_t)(l * 12 + 8) * KBSZ;
        const unsigned short* W1s_pk = pkEm1 + (size_t)(l * 12 + 0) * KBSZ;
        const unsigned short* W1d_pk = pkEm1 + (size_t)(l * 12 + 4) * KBSZ;
        const unsigned short* W1e_pk = pkEm1 + (size_t)(l * 12 + 8) * KBSZ;
        const unsigned short* PW_pk  = pkPost + (size_t)l * 52 * KBSZ;
        const unsigned short* lin_pk = pkLin + (size_t)l * 4 * KBSZ;
        const unsigned short* em2_pk = pkEm2 + (size_t)l * 4 * KBSZ;
        const float* pbl = preb + l * HD;
        const float* pob = postb + l * HD;
        const float* lb  = linb + l * HD;
        const float* g_  = bng + l * HD;
        const float* b_  = bnb + l * HD;
        const float* e1b = em1b + l * HD;
        const float* e2b = em2b + l * HD;

        hipMemsetAsync(stats + 128, 0, 256 * sizeof(float), stream);

        k_gemm2_Tb<4><<<gn, 256, 0, stream>>>(out_x, Wd_pk, Ws_pk, pbl, xdb, xsb, NN);
        if (l == 0)
            k_msg_T<1><<<ge, 256, 0, stream>>>(eatr, pkWe0f, bfold, xsb, srcp, sppos, mbuf);
        else
            k_msg_T<4><<<ge, 256, 0, stream>>>(out_ea, We_pk, nullptr, xsb, srcp, sppos, mbuf);
        k_agg<<<(NN + 3) / 4, 256, 0, stream>>>(mbuf, row_start, xdb, stats, aggb);
        k_post_lin_T<<<gn, 256, 0, stream>>>(out_x, aggb, PW_pk, pob, lin_pk, lb, outb, NN);
        k_bnstats<<<256, 256, 0, stream>>>(outb, stats + 128, stats + 256, NN);
        k_xupdate<<<NN * 32 / 256, 256, 0, stream>>>(out_x, outb, stats + 128, stats + 256, g_, b_);
        k_gemm2_Tb<4><<<gn, 256, 0, stream>>>(out_x, W1d_pk, W1s_pk, e1b, xdb, xsb, NN);
        k_edge_upd_T<<<ge, 256, 0, stream>>>(out_ea, W1e_pk, em2_pk, e2b, xsb, xdb, srcp, dstp);
    }
}